// Round 6
// baseline (748.697 us; speedup 1.0000x reference)
//
#include <hip/hip_runtime.h>
#include <stdint.h>

// C=32 captions, I=32 images, T=40 words, R=36 regions, D=1024.
// Inputs fp32 (reference setup_inputs); OUTPUT score [32,32] is FLOAT32
// (harness: reference output dtype; prior rounds wrote bf16 -> half-empty buffer).
// score[i,c] = sum over 2 IMRAM iterations of mean_t cosine(cap[c,t], wc[c,i,t]).
// Iter-2 gated memory is dead code. Iter-1 query==cap (broadcast over i) ->
// cat@W splits into cap@W_top (1280 rows, precomputed) + wc@W_bot (40960 rows).
// All kernels use <=60KB static LDS.

typedef unsigned short u16;
typedef __attribute__((ext_vector_type(8))) short bf16x8;
typedef __attribute__((ext_vector_type(4))) float f32x4;

#define MFMA_BF16(a, b, c) __builtin_amdgcn_mfma_f32_16x16x32_bf16((a), (b), (c), 0, 0, 0)

__device__ __forceinline__ float bf2f(u16 u) {
  union { unsigned v; float f; } x; x.v = ((unsigned)u) << 16; return x.f;
}
__device__ __forceinline__ u16 f2bf(float f) {  // round-to-nearest-even
  union { float f; unsigned v; } x; x.f = f;
  return (u16)((x.v + 0x7fffu + ((x.v >> 16) & 1u)) >> 16);
}

// ---------------------------------------------------------------------------
// Transpose+convert W fp32 [2048][1024] -> WT bf16 [1024][2048].
__global__ void transpose_k(const float* __restrict__ Wl, const float* __restrict__ Wg,
                            u16* __restrict__ WTl, u16* __restrict__ WTg) {
  __shared__ u16 tile[32][33];
  const float* src = blockIdx.z ? Wg : Wl;
  u16* dst = blockIdx.z ? WTg : WTl;
  const int k0 = blockIdx.x * 32, n0 = blockIdx.y * 32;
  const int tx = threadIdx.x, ty = threadIdx.y;
#pragma unroll
  for (int j = 0; j < 4; ++j)
    tile[ty + 8 * j][tx] = f2bf(src[(size_t)(k0 + ty + 8 * j) * 1024 + n0 + tx]);
  __syncthreads();
#pragma unroll
  for (int j = 0; j < 4; ++j)
    dst[(size_t)(n0 + ty + 8 * j) * 2048 + k0 + tx] = tile[tx][ty + 8 * j];
}

// ---------------------------------------------------------------------------
// capnorm[c*40+t] = ||cap[c,t,:]|| (fp32 input)
__global__ void capnorm_k(const float* __restrict__ cap, float* __restrict__ cnorm) {
  const int wv = threadIdx.x >> 6, lane = threadIdx.x & 63;
  const int row = blockIdx.x * 4 + wv;  // < 1280
  const float* p = cap + ((size_t)row << 10) + lane * 16;
  float s = 0.f;
#pragma unroll
  for (int e = 0; e < 16; ++e) { float v = p[e]; s += v * v; }
#pragma unroll
  for (int off = 32; off > 0; off >>= 1) s += __shfl_down(s, off, 64);
  if (lane == 0) cnorm[row] = sqrtf(s);
}

// ---------------------------------------------------------------------------
// Pre-GEMM: pre{L,G}[ct,n] = sum_k cap[ct,k]*W{l,g}[k][n], K=1024, bf16 out.
// A fp32 converted during staging. 128x128 tile, BK=32, grid 80.
__global__ __launch_bounds__(256, 2) void gemm_pre(
    const float* __restrict__ capf, const u16* __restrict__ WTl,
    const u16* __restrict__ WTg, u16* __restrict__ outL, u16* __restrict__ outG) {
  __shared__ __align__(16) u16 lsA[128 * 32];
  __shared__ __align__(16) u16 lsBl[128 * 32];
  __shared__ __align__(16) u16 lsBg[128 * 32];
  const int tid = threadIdx.x;
  const int bm = blockIdx.x >> 3, bn = blockIdx.x & 7;
  const int wv = tid >> 6, lane = tid & 63;
  const int quad = lane >> 4, l15 = lane & 15;
  const int wm = (wv & 1) << 6, wn = (wv >> 1) << 6;

  f32x4 accL[4][4], accG[4][4];
#pragma unroll
  for (int a = 0; a < 4; ++a)
#pragma unroll
    for (int b = 0; b < 4; ++b) {
      accL[a][b] = (f32x4){0.f, 0.f, 0.f, 0.f};
      accG[a][b] = (f32x4){0.f, 0.f, 0.f, 0.f};
    }

  const size_t arow0 = (size_t)bm * 128 * 1024;
  for (int kt = 0; kt < 32; ++kt) {
    if (kt) __syncthreads();
#pragma unroll
    for (int s = 0; s < 2; ++s) {
      const int idx = s * 256 + tid;
      const int row = idx >> 2, c8 = idx & 3;
      const float* srcA = capf + arow0 + (size_t)row * 1024 + kt * 32 + c8 * 8;
      const float4 v0 = *(const float4*)(srcA);
      const float4 v1 = *(const float4*)(srcA + 4);
      u16 o[8] = {f2bf(v0.x), f2bf(v0.y), f2bf(v0.z), f2bf(v0.w),
                  f2bf(v1.x), f2bf(v1.y), f2bf(v1.z), f2bf(v1.w)};
      *(uint4*)(lsA + row * 32 + c8 * 8) = *(const uint4*)o;
      const size_t bro = (size_t)(bn * 128 + row) * 2048 + kt * 32 + c8 * 8;
      *(uint4*)(lsBl + row * 32 + c8 * 8) = *(const uint4*)(WTl + bro);
      *(uint4*)(lsBg + row * 32 + c8 * 8) = *(const uint4*)(WTg + bro);
    }
    __syncthreads();
    bf16x8 af[4], bl8[4], bg8[4];
#pragma unroll
    for (int mt = 0; mt < 4; ++mt)
      af[mt] = *(const bf16x8*)(lsA + (wm + mt * 16 + l15) * 32 + quad * 8);
#pragma unroll
    for (int nt = 0; nt < 4; ++nt) {
      bl8[nt] = *(const bf16x8*)(lsBl + (wn + nt * 16 + l15) * 32 + quad * 8);
      bg8[nt] = *(const bf16x8*)(lsBg + (wn + nt * 16 + l15) * 32 + quad * 8);
    }
#pragma unroll
    for (int mt = 0; mt < 4; ++mt)
#pragma unroll
      for (int nt = 0; nt < 4; ++nt) {
        accL[mt][nt] = MFMA_BF16(af[mt], bl8[nt], accL[mt][nt]);
        accG[mt][nt] = MFMA_BF16(af[mt], bg8[nt], accG[mt][nt]);
      }
  }
#pragma unroll
  for (int mt = 0; mt < 4; ++mt)
#pragma unroll
    for (int nt = 0; nt < 4; ++nt)
#pragma unroll
      for (int r = 0; r < 4; ++r) {
        const int m = bm * 128 + wm + mt * 16 + quad * 4 + r;
        const int n = bn * 128 + wn + nt * 16 + l15;
        outL[(size_t)m * 1024 + n] = f2bf(accL[mt][nt][r]);
        outG[(size_t)m * 1024 + n] = f2bf(accG[mt][nt][r]);
      }
}

// ---------------------------------------------------------------------------
// Gated-memory GEMM (24KB LDS): q2 = cap*g + tanh(wc1@Wb + pre + b)*(1-g).
// M=40960, 128x128 tile, grid 2560. Reads wc1 bf16, writes separate q2 bf16.
__global__ __launch_bounds__(256, 2) void gemm_dual1(
    const u16* __restrict__ A, const u16* __restrict__ WTl, const u16* __restrict__ WTg,
    const u16* __restrict__ preL, const u16* __restrict__ preG,
    const float* __restrict__ capf, const float* __restrict__ bL,
    const float* __restrict__ bG, u16* __restrict__ q2) {
  __shared__ __align__(16) u16 lsA[128 * 32];
  __shared__ __align__(16) u16 lsBl[128 * 32];
  __shared__ __align__(16) u16 lsBg[128 * 32];
  const int tid = threadIdx.x;
  const int bm = blockIdx.x >> 3, bn = blockIdx.x & 7;
  const int wv = tid >> 6, lane = tid & 63;
  const int quad = lane >> 4, l15 = lane & 15;
  const int wm = (wv & 1) << 6, wn = (wv >> 1) << 6;

  f32x4 accL[4][4], accG[4][4];
#pragma unroll
  for (int a = 0; a < 4; ++a)
#pragma unroll
    for (int b = 0; b < 4; ++b) {
      accL[a][b] = (f32x4){0.f, 0.f, 0.f, 0.f};
      accG[a][b] = (f32x4){0.f, 0.f, 0.f, 0.f};
    }

  const size_t arow0 = (size_t)bm * 128 * 1024;
  for (int kt = 0; kt < 32; ++kt) {
    if (kt) __syncthreads();
#pragma unroll
    for (int s = 0; s < 2; ++s) {
      const int idx = s * 256 + tid;
      const int row = idx >> 2, c8 = idx & 3;
      *(uint4*)(lsA + row * 32 + c8 * 8) =
          *(const uint4*)(A + arow0 + (size_t)row * 1024 + kt * 32 + c8 * 8);
      const size_t bro = (size_t)(bn * 128 + row) * 2048 + 1024 + kt * 32 + c8 * 8;
      *(uint4*)(lsBl + row * 32 + c8 * 8) = *(const uint4*)(WTl + bro);
      *(uint4*)(lsBg + row * 32 + c8 * 8) = *(const uint4*)(WTg + bro);
    }
    __syncthreads();
    bf16x8 af[4], bl8[4], bg8[4];
#pragma unroll
    for (int mt = 0; mt < 4; ++mt)
      af[mt] = *(const bf16x8*)(lsA + (wm + mt * 16 + l15) * 32 + quad * 8);
#pragma unroll
    for (int nt = 0; nt < 4; ++nt) {
      bl8[nt] = *(const bf16x8*)(lsBl + (wn + nt * 16 + l15) * 32 + quad * 8);
      bg8[nt] = *(const bf16x8*)(lsBg + (wn + nt * 16 + l15) * 32 + quad * 8);
    }
#pragma unroll
    for (int mt = 0; mt < 4; ++mt)
#pragma unroll
      for (int nt = 0; nt < 4; ++nt) {
        accL[mt][nt] = MFMA_BF16(af[mt], bl8[nt], accL[mt][nt]);
        accG[mt][nt] = MFMA_BF16(af[mt], bg8[nt], accG[mt][nt]);
      }
  }
#pragma unroll
  for (int mt = 0; mt < 4; ++mt)
#pragma unroll
    for (int nt = 0; nt < 4; ++nt)
#pragma unroll
      for (int r = 0; r < 4; ++r) {
        const int m = bm * 128 + wm + mt * 16 + quad * 4 + r;
        const int n = bn * 128 + wn + nt * 16 + l15;
        const int c = m / 1280;            // m = (c*32+i)*40 + t
        const int t = (m - c * 1280) % 40;
        const int ct = c * 40 + t;
        const float aL = accL[mt][nt][r] + bf2f(preL[(size_t)ct * 1024 + n]) + bL[n];
        const float aG = accG[mt][nt][r] + bf2f(preG[(size_t)ct * 1024 + n]) + bG[n];
        const float g = 1.f / (1.f + __expf(-aG));
        const float u = 2.f / (1.f + __expf(-2.f * aL)) - 1.f;  // tanh
        const float cv = capf[(size_t)ct * 1024 + n];
        q2[(size_t)m * 1024 + n] = f2bf(cv * g + u * (1.f - g));
      }
}

// ---------------------------------------------------------------------------
// Fused attention per (c,i). ITER 1: query=cap (fp32), writes wc1 bf16 + sim1.
// ITER 2: query=q2 (bf16), writes score (FLOAT32) = sim1 + sim2. 60KB LDS.
template <int ITER>
__global__ __launch_bounds__(256, 2) void attn_k(
    const float* __restrict__ ctxf, const float* __restrict__ capf,
    const u16* __restrict__ q2, u16* __restrict__ wc1, const float* __restrict__ cnorm,
    float* __restrict__ sim1, float* __restrict__ score) {
  __shared__ __align__(16) u16 lsC[48 * 136];
  __shared__ __align__(16) u16 lsQ[48 * 136];
  __shared__ float lsS[48 * 48];
  __shared__ __align__(16) u16 lsAT[48 * 72];
  __shared__ __align__(16) u16 lsCT[128 * 72];
  __shared__ float lsRN[48], lsCOS[48], lsWN[48], lsRED[48];

  const int tid = threadIdx.x;
  const int c = blockIdx.x >> 5, i = blockIdx.x & 31;
  const int wv = tid >> 6, lane = tid & 63;
  const int quad = lane >> 4, l15 = lane & 15;

  {  // zero LDS (pads must be 0; lsS/lsCOS/lsWN accumulate)
    unsigned* z1 = (unsigned*)lsC;  for (int k = tid; k < 3264; k += 256) z1[k] = 0u;
    unsigned* z2 = (unsigned*)lsQ;  for (int k = tid; k < 3264; k += 256) z2[k] = 0u;
    for (int k = tid; k < 2304; k += 256) lsS[k] = 0.f;
    unsigned* z3 = (unsigned*)lsAT; for (int k = tid; k < 1728; k += 256) z3[k] = 0u;
    unsigned* z4 = (unsigned*)lsCT; for (int k = tid; k < 4608; k += 256) z4[k] = 0u;
    if (tid < 48) { lsCOS[tid] = 0.f; lsWN[tid] = 0.f; }
  }

  const float* xbf = ctxf + (((size_t)i * 36) << 10);
  const float* cbf = capf + (((size_t)c * 40) << 10);
  const u16* qb2 = q2 + (((size_t)(c * 32 + i) * 40) << 10);

  // ---- phase 1: S[r][t] via MFMA, K split across waves
  f32x4 accS[3][3];
#pragma unroll
  for (int a = 0; a < 3; ++a)
#pragma unroll
    for (int b = 0; b < 3; ++b) accS[a][b] = (f32x4){0.f, 0.f, 0.f, 0.f};

  for (int ch = 0; ch < 8; ++ch) {
    __syncthreads();
    for (int idx = tid; idx < 1152; idx += 256) {  // ctx: 36 rows * 32 units of 4
      const int r = idx >> 5, cc = idx & 31;
      const float4 v = *(const float4*)(xbf + ((size_t)r << 10) + ch * 128 + cc * 4);
      u16 o[4] = {f2bf(v.x), f2bf(v.y), f2bf(v.z), f2bf(v.w)};
      *(uint2*)(lsC + r * 136 + cc * 4) = *(const uint2*)o;
    }
    for (int idx = tid; idx < 1280; idx += 256) {  // query: 40 rows * 32 units of 4
      const int t = idx >> 5, cc = idx & 31;
      if (ITER == 1) {
        const float4 v = *(const float4*)(cbf + ((size_t)t << 10) + ch * 128 + cc * 4);
        u16 o[4] = {f2bf(v.x), f2bf(v.y), f2bf(v.z), f2bf(v.w)};
        *(uint2*)(lsQ + t * 136 + cc * 4) = *(const uint2*)o;
      } else {
        *(uint2*)(lsQ + t * 136 + cc * 4) =
            *(const uint2*)(qb2 + ((size_t)t << 10) + ch * 128 + cc * 4);
      }
    }
    __syncthreads();
    bf16x8 af[3], bq[3];
#pragma unroll
    for (int mt = 0; mt < 3; ++mt)
      af[mt] = *(const bf16x8*)(lsC + (mt * 16 + l15) * 136 + wv * 32 + quad * 8);
#pragma unroll
    for (int nt = 0; nt < 3; ++nt)
      bq[nt] = *(const bf16x8*)(lsQ + (nt * 16 + l15) * 136 + wv * 32 + quad * 8);
#pragma unroll
    for (int mt = 0; mt < 3; ++mt)
#pragma unroll
      for (int nt = 0; nt < 3; ++nt) accS[mt][nt] = MFMA_BF16(af[mt], bq[nt], accS[mt][nt]);
  }
  __syncthreads();
#pragma unroll
  for (int mt = 0; mt < 3; ++mt)
#pragma unroll
    for (int nt = 0; nt < 3; ++nt)
#pragma unroll
      for (int r = 0; r < 4; ++r)
        atomicAdd(&lsS[(mt * 16 + quad * 4 + r) * 48 + nt * 16 + l15], accS[mt][nt][r]);
  __syncthreads();

  // ---- leaky + l2norm over t (per region r)
  if (tid < 36) {
    float s2 = 0.f;
#pragma unroll
    for (int t = 0; t < 40; ++t) {
      float v = lsS[tid * 48 + t]; v = v > 0.f ? v : 0.1f * v; s2 += v * v;
    }
    lsRN[tid] = sqrtf(s2) + 1e-8f;
  }
  __syncthreads();
  // ---- temperature softmax over r (per word t); write attn^T bf16 [t][r]
  if (tid < 40) {
    float vals[36]; float mx = -3.4e38f;
#pragma unroll
    for (int r = 0; r < 36; ++r) {
      float v = lsS[r * 48 + tid]; v = v > 0.f ? v : 0.1f * v;
      v = 9.f * v / lsRN[r]; vals[r] = v; mx = fmaxf(mx, v);
    }
    float ss = 0.f;
#pragma unroll
    for (int r = 0; r < 36; ++r) { float e = __expf(vals[r] - mx); vals[r] = e; ss += e; }
    const float inv = 1.f / ss;
#pragma unroll
    for (int r = 0; r < 36; ++r) lsAT[tid * 72 + r] = f2bf(vals[r] * inv);
  }
  __syncthreads();

  // ---- phase 2: wc = attn@ctx via MFMA (K=r padded to 64); fused cosine
  float pn[12], pw[12];
#pragma unroll
  for (int k = 0; k < 12; ++k) { pn[k] = 0.f; pw[k] = 0.f; }

  for (int ch = 0; ch < 8; ++ch) {
    if (ch) __syncthreads();
    for (int idx = tid; idx < 1152; idx += 256) {  // transposed stage: lsCT[d][r]
      const int r = idx >> 5, cc = idx & 31;
      const float4 v = *(const float4*)(xbf + ((size_t)r << 10) + ch * 128 + cc * 4);
      u16 o[4] = {f2bf(v.x), f2bf(v.y), f2bf(v.z), f2bf(v.w)};
#pragma unroll
      for (int e = 0; e < 4; ++e) lsCT[(cc * 4 + e) * 72 + r] = o[e];
    }
    __syncthreads();
    f32x4 accW[3][2];
#pragma unroll
    for (int a = 0; a < 3; ++a)
#pragma unroll
      for (int b = 0; b < 2; ++b) accW[a][b] = (f32x4){0.f, 0.f, 0.f, 0.f};
#pragma unroll
    for (int ks = 0; ks < 2; ++ks) {
      bf16x8 aA[3], bC[2];
#pragma unroll
      for (int mt = 0; mt < 3; ++mt)
        aA[mt] = *(const bf16x8*)(lsAT + (mt * 16 + l15) * 72 + ks * 32 + quad * 8);
#pragma unroll
      for (int nt = 0; nt < 2; ++nt)
        bC[nt] = *(const bf16x8*)(lsCT + (wv * 32 + nt * 16 + l15) * 72 + ks * 32 + quad * 8);
#pragma unroll
      for (int mt = 0; mt < 3; ++mt)
#pragma unroll
        for (int nt = 0; nt < 2; ++nt) accW[mt][nt] = MFMA_BF16(aA[mt], bC[nt], accW[mt][nt]);
    }
#pragma unroll
    for (int mt = 0; mt < 3; ++mt)
#pragma unroll
      for (int r = 0; r < 4; ++r) {
        const int t = mt * 16 + quad * 4 + r;
        if (t < 40) {
#pragma unroll
          for (int nt = 0; nt < 2; ++nt) {
            const int d = ch * 128 + wv * 32 + nt * 16 + l15;
            const float w = accW[mt][nt][r];
            const float cv = cbf[((size_t)t << 10) + d];
            pn[mt * 4 + r] += cv * w;
            pw[mt * 4 + r] += w * w;
            if (ITER == 1)
              wc1[(((size_t)(c * 32 + i) * 40 + t) << 10) + d] = f2bf(w);
          }
        }
      }
  }
#pragma unroll
  for (int mt = 0; mt < 3; ++mt)
#pragma unroll
    for (int r = 0; r < 4; ++r) {
      const int t = mt * 16 + quad * 4 + r;
      if (t < 40) {
        atomicAdd(&lsCOS[t], pn[mt * 4 + r]);
        atomicAdd(&lsWN[t], pw[mt * 4 + r]);
      }
    }
  __syncthreads();
  if (tid < 40) {
    const float w1 = cnorm[c * 40 + tid];
    const float w2 = sqrtf(lsWN[tid]);
    lsRED[tid] = lsCOS[tid] / fmaxf(w1 * w2, 1e-8f);
  }
  __syncthreads();
  if (tid == 0) {
    float s = 0.f;
    for (int t = 0; t < 40; ++t) s += lsRED[t];
    s *= (1.f / 40.f);
    if (ITER == 1) sim1[c * 32 + i] = s;
    else score[i * 32 + c] = s + sim1[c * 32 + i];   // FLOAT32 output
  }
}

// ---------------------------------------------------------------------------
extern "C" void kernel_launch(void* const* d_in, const int* in_sizes, int n_in,
                              void* d_out, int out_size, void* d_ws, size_t ws_size,
                              hipStream_t stream) {
  const float* img = (const float*)d_in[0];   // [32][36][1024] fp32
  const float* cap = (const float*)d_in[1];   // [32][40][1024] fp32
  const float* Wl  = (const float*)d_in[2];   // [2048][1024] fp32
  const float* bl  = (const float*)d_in[3];   // [1024] fp32
  const float* Wg  = (const float*)d_in[4];
  const float* bg  = (const float*)d_in[5];
  float* out = (float*)d_out;                 // [32][32] fp32

  char* ws = (char*)d_ws;                 // total ~181.4 MB
  float* cnrm = (float*)ws;               ws += 5120;
  float* sim1 = (float*)ws;               ws += 4096;
  u16*   WTl  = (u16*)ws;                 ws += (size_t)1024 * 2048 * 2;   // 4.2 MB
  u16*   WTg  = (u16*)ws;                 ws += (size_t)1024 * 2048 * 2;   // 4.2 MB
  u16*   preL = (u16*)ws;                 ws += (size_t)1280 * 1024 * 2;   // 2.6 MB
  u16*   preG = (u16*)ws;                 ws += (size_t)1280 * 1024 * 2;   // 2.6 MB
  u16*   wc1  = (u16*)ws;                 ws += (size_t)40960 * 1024 * 2;  // 83.9 MB
  u16*   q2   = (u16*)ws;                 ws += (size_t)40960 * 1024 * 2;  // 83.9 MB

  transpose_k<<<dim3(64, 32, 2), dim3(32, 8), 0, stream>>>(Wl, Wg, WTl, WTg);
  capnorm_k<<<320, 256, 0, stream>>>(cap, cnrm);
  gemm_pre<<<80, 256, 0, stream>>>(cap, WTl, WTg, preL, preG);
  attn_k<1><<<1024, 256, 0, stream>>>(img, cap, q2, wc1, cnrm, sim1, out);
  gemm_dual1<<<2560, 256, 0, stream>>>(wc1, WTl, WTg, preL, preG, cap, bl, bg, q2);
  attn_k<2><<<1024, 256, 0, stream>>>(img, cap, q2, wc1, cnrm, sim1, out);
}

// Round 7
// 583.353 us; speedup vs baseline: 1.2834x; 1.2834x over previous
//
#include <hip/hip_runtime.h>
#include <stdint.h>

// C=32 captions, I=32 images, T=40 words, R=36 regions, D=1024.
// Inputs fp32; output score [32,32] fp32.
// Iter-2 gated memory dead; iter-1 query==cap -> pre-GEMM split.
// R7: attn_k rewritten barrier-free: direct-from-global MFMA frags,
// in-register shuffle softmax, per-wave LDS for C->A layout transform.
// ws total 186,393,856 B < proven-safe 186,655,744 (capb aliases q2 head).

typedef unsigned short u16;
typedef __attribute__((ext_vector_type(8))) short bf16x8;
typedef __attribute__((ext_vector_type(4))) float f32x4;

#define MFMA_BF16(a, b, c) __builtin_amdgcn_mfma_f32_16x16x32_bf16((a), (b), (c), 0, 0, 0)

__device__ __forceinline__ float bf2f(u16 u) {
  union { unsigned v; float f; } x; x.v = ((unsigned)u) << 16; return x.f;
}
__device__ __forceinline__ u16 f2bf(float f) {  // round-to-nearest-even
  union { float f; unsigned v; } x; x.f = f;
  return (u16)((x.v + 0x7fffu + ((x.v >> 16) & 1u)) >> 16);
}

// ---------------------------------------------------------------------------
// fp32 -> bf16 convert, 4 elems/thread (n = grid*1024).
__global__ void cvt_k(const float* __restrict__ src, u16* __restrict__ dst) {
  const int idx = (blockIdx.x * 256 + threadIdx.x) * 4;
  const float4 v = *(const float4*)(src + idx);
  u16 o[4] = {f2bf(v.x), f2bf(v.y), f2bf(v.z), f2bf(v.w)};
  *(uint2*)(dst + idx) = *(const uint2*)o;
}

// ---------------------------------------------------------------------------
// Build ctxT[i][d][40] bf16 from img fp32 [i][r][d]; r pad 36..39 = 0.
// Thread per (i,d). Row = 40 u16 = 80 B (16B-aligned), written as 5 uint4.
__global__ void ctxt_k(const float* __restrict__ img, u16* __restrict__ ctxT) {
  const int g = blockIdx.x * 256 + threadIdx.x;  // 32768 = 32 i * 1024 d
  const int i = g >> 10, d = g & 1023;
  u16 row[40];
#pragma unroll
  for (int r = 0; r < 36; ++r) row[r] = f2bf(img[((size_t)(i * 36 + r) << 10) + d]);
#pragma unroll
  for (int r = 36; r < 40; ++r) row[r] = 0;
  u16* dst = ctxT + (size_t)g * 40;
#pragma unroll
  for (int j = 0; j < 5; ++j) *(uint4*)(dst + j * 8) = *(const uint4*)(row + j * 8);
}

// ---------------------------------------------------------------------------
// capnorm[c*40+t] = ||cap[c,t,:]|| (fp32 input)
__global__ void capnorm_k(const float* __restrict__ cap, float* __restrict__ cnorm) {
  const int wv = threadIdx.x >> 6, lane = threadIdx.x & 63;
  const int row = blockIdx.x * 4 + wv;  // < 1280
  const float* p = cap + ((size_t)row << 10) + lane * 16;
  float s = 0.f;
#pragma unroll
  for (int e = 0; e < 16; ++e) { float v = p[e]; s += v * v; }
#pragma unroll
  for (int off = 32; off > 0; off >>= 1) s += __shfl_down(s, off, 64);
  if (lane == 0) cnorm[row] = sqrtf(s);
}

// ---------------------------------------------------------------------------
// Transpose+convert W fp32 [2048][1024] -> WT bf16 [1024][2048].
__global__ void transpose_k(const float* __restrict__ Wl, const float* __restrict__ Wg,
                            u16* __restrict__ WTl, u16* __restrict__ WTg) {
  __shared__ u16 tile[32][33];
  const float* src = blockIdx.z ? Wg : Wl;
  u16* dst = blockIdx.z ? WTg : WTl;
  const int k0 = blockIdx.x * 32, n0 = blockIdx.y * 32;
  const int tx = threadIdx.x, ty = threadIdx.y;
#pragma unroll
  for (int j = 0; j < 4; ++j)
    tile[ty + 8 * j][tx] = f2bf(src[(size_t)(k0 + ty + 8 * j) * 1024 + n0 + tx]);
  __syncthreads();
#pragma unroll
  for (int j = 0; j < 4; ++j)
    dst[(size_t)(n0 + ty + 8 * j) * 2048 + k0 + tx] = tile[tx][ty + 8 * j];
}

// ---------------------------------------------------------------------------
// Pre-GEMM: pre{L,G}[ct,n] = sum_k cap[ct,k]*W{l,g}[k][n], K=1024, bf16 out.
__global__ __launch_bounds__(256, 2) void gemm_pre(
    const float* __restrict__ capf, const u16* __restrict__ WTl,
    const u16* __restrict__ WTg, u16* __restrict__ outL, u16* __restrict__ outG) {
  __shared__ __align__(16) u16 lsA[128 * 32];
  __shared__ __align__(16) u16 lsBl[128 * 32];
  __shared__ __align__(16) u16 lsBg[128 * 32];
  const int tid = threadIdx.x;
  const int bm = blockIdx.x >> 3, bn = blockIdx.x & 7;
  const int wv = tid >> 6, lane = tid & 63;
  const int quad = lane >> 4, l15 = lane & 15;
  const int wm = (wv & 1) << 6, wn = (wv >> 1) << 6;

  f32x4 accL[4][4], accG[4][4];
#pragma unroll
  for (int a = 0; a < 4; ++a)
#pragma unroll
    for (int b = 0; b < 4; ++b) {
      accL[a][b] = (f32x4){0.f, 0.f, 0.f, 0.f};
      accG[a][b] = (f32x4){0.f, 0.f, 0.f, 0.f};
    }

  const size_t arow0 = (size_t)bm * 128 * 1024;
  for (int kt = 0; kt < 32; ++kt) {
    if (kt) __syncthreads();
#pragma unroll
    for (int s = 0; s < 2; ++s) {
      const int idx = s * 256 + tid;
      const int row = idx >> 2, c8 = idx & 3;
      const float* srcA = capf + arow0 + (size_t)row * 1024 + kt * 32 + c8 * 8;
      const float4 v0 = *(const float4*)(srcA);
      const float4 v1 = *(const float4*)(srcA + 4);
      u16 o[8] = {f2bf(v0.x), f2bf(v0.y), f2bf(v0.z), f2bf(v0.w),
                  f2bf(v1.x), f2bf(v1.y), f2bf(v1.z), f2bf(v1.w)};
      *(uint4*)(lsA + row * 32 + c8 * 8) = *(const uint4*)o;
      const size_t bro = (size_t)(bn * 128 + row) * 2048 + kt * 32 + c8 * 8;
      *(uint4*)(lsBl + row * 32 + c8 * 8) = *(const uint4*)(WTl + bro);
      *(uint4*)(lsBg + row * 32 + c8 * 8) = *(const uint4*)(WTg + bro);
    }
    __syncthreads();
    bf16x8 af[4], bl8[4], bg8[4];
#pragma unroll
    for (int mt = 0; mt < 4; ++mt)
      af[mt] = *(const bf16x8*)(lsA + (wm + mt * 16 + l15) * 32 + quad * 8);
#pragma unroll
    for (int nt = 0; nt < 4; ++nt) {
      bl8[nt] = *(const bf16x8*)(lsBl + (wn + nt * 16 + l15) * 32 + quad * 8);
      bg8[nt] = *(const bf16x8*)(lsBg + (wn + nt * 16 + l15) * 32 + quad * 8);
    }
#pragma unroll
    for (int mt = 0; mt < 4; ++mt)
#pragma unroll
      for (int nt = 0; nt < 4; ++nt) {
        accL[mt][nt] = MFMA_BF16(af[mt], bl8[nt], accL[mt][nt]);
        accG[mt][nt] = MFMA_BF16(af[mt], bg8[nt], accG[mt][nt]);
      }
  }
#pragma unroll
  for (int mt = 0; mt < 4; ++mt)
#pragma unroll
    for (int nt = 0; nt < 4; ++nt)
#pragma unroll
      for (int r = 0; r < 4; ++r) {
        const int m = bm * 128 + wm + mt * 16 + quad * 4 + r;
        const int n = bn * 128 + wn + nt * 16 + l15;
        outL[(size_t)m * 1024 + n] = f2bf(accL[mt][nt][r]);
        outG[(size_t)m * 1024 + n] = f2bf(accG[mt][nt][r]);
      }
}

// ---------------------------------------------------------------------------
// Gated-memory GEMM: q2 = cap*g + tanh(wc1@Wb + pre + b)*(1-g). Grid 2560.
__global__ __launch_bounds__(256, 2) void gemm_dual1(
    const u16* __restrict__ A, const u16* __restrict__ WTl, const u16* __restrict__ WTg,
    const u16* __restrict__ preL, const u16* __restrict__ preG,
    const float* __restrict__ capf, const float* __restrict__ bL,
    const float* __restrict__ bG, u16* __restrict__ q2) {
  __shared__ __align__(16) u16 lsA[128 * 32];
  __shared__ __align__(16) u16 lsBl[128 * 32];
  __shared__ __align__(16) u16 lsBg[128 * 32];
  const int tid = threadIdx.x;
  const int bm = blockIdx.x >> 3, bn = blockIdx.x & 7;
  const int wv = tid >> 6, lane = tid & 63;
  const int quad = lane >> 4, l15 = lane & 15;
  const int wm = (wv & 1) << 6, wn = (wv >> 1) << 6;

  f32x4 accL[4][4], accG[4][4];
#pragma unroll
  for (int a = 0; a < 4; ++a)
#pragma unroll
    for (int b = 0; b < 4; ++b) {
      accL[a][b] = (f32x4){0.f, 0.f, 0.f, 0.f};
      accG[a][b] = (f32x4){0.f, 0.f, 0.f, 0.f};
    }

  const size_t arow0 = (size_t)bm * 128 * 1024;
  for (int kt = 0; kt < 32; ++kt) {
    if (kt) __syncthreads();
#pragma unroll
    for (int s = 0; s < 2; ++s) {
      const int idx = s * 256 + tid;
      const int row = idx >> 2, c8 = idx & 3;
      *(uint4*)(lsA + row * 32 + c8 * 8) =
          *(const uint4*)(A + arow0 + (size_t)row * 1024 + kt * 32 + c8 * 8);
      const size_t bro = (size_t)(bn * 128 + row) * 2048 + 1024 + kt * 32 + c8 * 8;
      *(uint4*)(lsBl + row * 32 + c8 * 8) = *(const uint4*)(WTl + bro);
      *(uint4*)(lsBg + row * 32 + c8 * 8) = *(const uint4*)(WTg + bro);
    }
    __syncthreads();
    bf16x8 af[4], bl8[4], bg8[4];
#pragma unroll
    for (int mt = 0; mt < 4; ++mt)
      af[mt] = *(const bf16x8*)(lsA + (wm + mt * 16 + l15) * 32 + quad * 8);
#pragma unroll
    for (int nt = 0; nt < 4; ++nt) {
      bl8[nt] = *(const bf16x8*)(lsBl + (wn + nt * 16 + l15) * 32 + quad * 8);
      bg8[nt] = *(const bf16x8*)(lsBg + (wn + nt * 16 + l15) * 32 + quad * 8);
    }
#pragma unroll
    for (int mt = 0; mt < 4; ++mt)
#pragma unroll
      for (int nt = 0; nt < 4; ++nt) {
        accL[mt][nt] = MFMA_BF16(af[mt], bl8[nt], accL[mt][nt]);
        accG[mt][nt] = MFMA_BF16(af[mt], bg8[nt], accG[mt][nt]);
      }
  }
#pragma unroll
  for (int mt = 0; mt < 4; ++mt)
#pragma unroll
    for (int nt = 0; nt < 4; ++nt)
#pragma unroll
      for (int r = 0; r < 4; ++r) {
        const int m = bm * 128 + wm + mt * 16 + quad * 4 + r;
        const int n = bn * 128 + wn + nt * 16 + l15;
        const int c = m / 1280;            // m = (c*32+i)*40 + t
        const int t = (m - c * 1280) % 40;
        const int ct = c * 40 + t;
        const float aL = accL[mt][nt][r] + bf2f(preL[(size_t)ct * 1024 + n]) + bL[n];
        const float aG = accG[mt][nt][r] + bf2f(preG[(size_t)ct * 1024 + n]) + bG[n];
        const float g = 1.f / (1.f + __expf(-aG));
        const float u = 2.f / (1.f + __expf(-2.f * aL)) - 1.f;  // tanh
        const float cv = capf[(size_t)ct * 1024 + n];
        q2[(size_t)m * 1024 + n] = f2bf(cv * g + u * (1.f - g));
      }
}

// ---------------------------------------------------------------------------
// Barrier-free fused attention. Block = (c,i) pair, 4 waves.
// Phase 1 (redundant per wave): S[r][t] = ctx@q^T via direct-global MFMA frags.
// In-register leaky+l2norm (shfl over l15) + softmax over r (shfl over quads).
// attn -> per-wave lsAT (C->A layout, wave-ordered LDS, no barrier).
// Phase 2: wave wv covers d in [wv*256, wv*256+256): B-frags from ctxT[i][d][40].
// Fused cosine; 3 barriers total (final LDS reduction only).
template <int ITER>
__global__ __launch_bounds__(256, 2) void attn_k(
    const u16* __restrict__ imgb, const u16* __restrict__ capb,
    const u16* __restrict__ q2, const u16* __restrict__ ctxT,
    const float* __restrict__ capf, u16* __restrict__ wc1,
    const float* __restrict__ cnorm, float* __restrict__ sim1,
    float* __restrict__ score) {
  __shared__ __align__(16) u16 lsAT[4][48 * 72];  // per-wave attn, A-layout
  __shared__ float lsCOS[48], lsWN[48], lsRED[48];

  const int tid = threadIdx.x;
  const int c = blockIdx.x >> 5, i = blockIdx.x & 31;
  const int pair = c * 32 + i;
  const int wv = tid >> 6, lane = tid & 63;
  const int quad = lane >> 4, l15 = lane & 15;

  {  // zero this wave's lsAT; wave 0 zeros the reduction arrays
    unsigned* z = (unsigned*)lsAT[wv];
    for (int k = lane; k < 1728; k += 64) z[k] = 0u;
    if (tid < 48) { lsCOS[tid] = 0.f; lsWN[tid] = 0.f; }
  }

  // ---- phase 1: S = ctx @ q^T, full K=1024, frags direct from global
  const u16* arow[3]; bool avalid[3];
  const u16* brow[3]; bool bvalid[3];
#pragma unroll
  for (int mt = 0; mt < 3; ++mt) {
    const int r = mt * 16 + l15;
    avalid[mt] = r < 36;
    arow[mt] = imgb + ((size_t)(i * 36 + (r < 36 ? r : 35)) << 10);
  }
#pragma unroll
  for (int nt = 0; nt < 3; ++nt) {
    const int t = nt * 16 + l15;
    bvalid[nt] = t < 40;
    const int tc = t < 40 ? t : 39;
    brow[nt] = (ITER == 1) ? (capb + ((size_t)(c * 40 + tc) << 10))
                           : (q2 + ((size_t)(pair * 40 + tc) << 10));
  }
  const bf16x8 zero8 = {0, 0, 0, 0, 0, 0, 0, 0};

  f32x4 accS[3][3];
#pragma unroll
  for (int a = 0; a < 3; ++a)
#pragma unroll
    for (int b = 0; b < 3; ++b) accS[a][b] = (f32x4){0.f, 0.f, 0.f, 0.f};

  for (int kk = 0; kk < 32; ++kk) {
    const int ko = kk * 32 + quad * 8;
    bf16x8 af[3], bq[3];
#pragma unroll
    for (int mt = 0; mt < 3; ++mt)
      af[mt] = avalid[mt] ? *(const bf16x8*)(arow[mt] + ko) : zero8;
#pragma unroll
    for (int nt = 0; nt < 3; ++nt)
      bq[nt] = bvalid[nt] ? *(const bf16x8*)(brow[nt] + ko) : zero8;
#pragma unroll
    for (int mt = 0; mt < 3; ++mt)
#pragma unroll
      for (int nt = 0; nt < 3; ++nt)
        accS[mt][nt] = MFMA_BF16(af[mt], bq[nt], accS[mt][nt]);
  }

  // ---- in-register leaky + l2norm over t (r = mt*16+quad*4+rg, t = nt*16+l15)
  float rn[3][4];
#pragma unroll
  for (int mt = 0; mt < 3; ++mt)
#pragma unroll
    for (int rg = 0; rg < 4; ++rg) {
      float s2 = 0.f;
#pragma unroll
      for (int nt = 0; nt < 3; ++nt) {
        float v = accS[mt][nt][rg]; v = v > 0.f ? v : 0.1f * v; s2 += v * v;
      }
      s2 += __shfl_xor(s2, 1, 64); s2 += __shfl_xor(s2, 2, 64);
      s2 += __shfl_xor(s2, 4, 64); s2 += __shfl_xor(s2, 8, 64);
      rn[mt][rg] = sqrtf(s2) + 1e-8f;
    }
  // ---- softmax over r (masked r<36); z stored back into accS
  float mx[3] = {-3.0e38f, -3.0e38f, -3.0e38f};
#pragma unroll
  for (int mt = 0; mt < 3; ++mt)
#pragma unroll
    for (int nt = 0; nt < 3; ++nt)
#pragma unroll
      for (int rg = 0; rg < 4; ++rg) {
        const int r = mt * 16 + quad * 4 + rg;
        float v = accS[mt][nt][rg]; v = v > 0.f ? v : 0.1f * v;
        float zz = 9.f * v / rn[mt][rg];
        zz = (r < 36) ? zz : -3.0e38f;
        accS[mt][nt][rg] = zz;
        mx[nt] = fmaxf(mx[nt], zz);
      }
#pragma unroll
  for (int nt = 0; nt < 3; ++nt) {
    mx[nt] = fmaxf(mx[nt], __shfl_xor(mx[nt], 16, 64));
    mx[nt] = fmaxf(mx[nt], __shfl_xor(mx[nt], 32, 64));
  }
  float ss[3] = {0.f, 0.f, 0.f};
#pragma unroll
  for (int mt = 0; mt < 3; ++mt)
#pragma unroll
    for (int nt = 0; nt < 3; ++nt)
#pragma unroll
      for (int rg = 0; rg < 4; ++rg) {
        const float e = __expf(accS[mt][nt][rg] - mx[nt]);
        accS[mt][nt][rg] = e; ss[nt] += e;
      }
#pragma unroll
  for (int nt = 0; nt < 3; ++nt) {
    ss[nt] += __shfl_xor(ss[nt], 16, 64);
    ss[nt] += __shfl_xor(ss[nt], 32, 64);
    ss[nt] = 1.f / ss[nt];
  }
  // ---- write attn bf16 to per-wave lsAT in A-layout [t][r] (no barrier)
#pragma unroll
  for (int nt = 0; nt < 3; ++nt) {
    const int t = nt * 16 + l15;
    if (t < 40) {
#pragma unroll
      for (int mt = 0; mt < 3; ++mt)
#pragma unroll
        for (int rg = 0; rg < 4; ++rg)
          lsAT[wv][t * 72 + mt * 16 + quad * 4 + rg] = f2bf(accS[mt][nt][rg] * ss[nt]);
    }
  }

  // ---- phase 2: wc = attn @ ctx (wave's d-range), fused cosine
  bf16x8 afA[3][2];
#pragma unroll
  for (int mt2 = 0; mt2 < 3; ++mt2)
#pragma unroll
    for (int ks = 0; ks < 2; ++ks)
      afA[mt2][ks] = *(const bf16x8*)(lsAT[wv] + (mt2 * 16 + l15) * 72 + ks * 32 + quad * 8);

  float pn[12], pw[12];
#pragma unroll
  for (int k = 0; k < 12; ++k) { pn[k] = 0.f; pw[k] = 0.f; }

  const int dbase = wv * 256;
  for (int nt2 = 0; nt2 < 16; ++nt2) {
    const int d = dbase + nt2 * 16 + l15;
    const u16* bp = ctxT + ((size_t)(i << 10) + d) * 40;
    const bf16x8 b0 = *(const bf16x8*)(bp + quad * 8);
    const bf16x8 b1 = *(const bf16x8*)(bp + 32 + quad * 8);  // k>=40 overrun x0
    f32x4 acc[3];
#pragma unroll
    for (int mt2 = 0; mt2 < 3; ++mt2) {
      acc[mt2] = (f32x4){0.f, 0.f, 0.f, 0.f};
      acc[mt2] = MFMA_BF16(afA[mt2][0], b0, acc[mt2]);
      acc[mt2] = MFMA_BF16(afA[mt2][1], b1, acc[mt2]);
    }
#pragma unroll
    for (int mt2 = 0; mt2 < 3; ++mt2)
#pragma unroll
      for (int rg = 0; rg < 4; ++rg) {
        const int t = mt2 * 16 + quad * 4 + rg;
        if (t < 40) {
          const float w = acc[mt2][rg];
          const float cv = capf[((size_t)(c * 40 + t) << 10) + d];
          pn[mt2 * 4 + rg] += cv * w;
          pw[mt2 * 4 + rg] += w * w;
          if (ITER == 1) wc1[(((size_t)pair * 40 + t) << 10) + d] = f2bf(w);
        }
      }
  }
  // ---- reduce cosine partials over d-lanes (l15 butterfly)
#pragma unroll
  for (int k = 0; k < 12; ++k) {
#pragma unroll
    for (int off = 1; off <= 8; off <<= 1) {
      pn[k] += __shfl_xor(pn[k], off, 64);
      pw[k] += __shfl_xor(pw[k], off, 64);
    }
  }
  __syncthreads();  // zero-init of lsCOS/lsWN visible; all waves ready
  if (l15 == 0) {
#pragma unroll
    for (int mt2 = 0; mt2 < 3; ++mt2)
#pragma unroll
      for (int rg = 0; rg < 4; ++rg) {
        const int t = mt2 * 16 + quad * 4 + rg;
        if (t < 40) {
          atomicAdd(&lsCOS[t], pn[mt2 * 4 + rg]);
          atomicAdd(&lsWN[t], pw[mt2 * 4 + rg]);
        }
      }
  }
  __syncthreads();
  if (tid < 40) {
    const float w2 = sqrtf(lsWN[tid]);
    lsRED[tid] = lsCOS[tid] / fmaxf(cnorm[c * 40 + tid] * w2, 1e-8f);
  }
  __syncthreads();
  if (tid == 0) {
    float s = 0.f;
    for (int t = 0; t < 40; ++t) s += lsRED[t];
    s *= (1.f / 40.f);
    if (ITER == 1) sim1[pair] = s;
    else score[i * 32 + c] = s + sim1[pair];
  }
}

// ---------------------------------------------------------------------------
extern "C" void kernel_launch(void* const* d_in, const int* in_sizes, int n_in,
                              void* d_out, int out_size, void* d_ws, size_t ws_size,
                              hipStream_t stream) {
  const float* img = (const float*)d_in[0];   // [32][36][1024] fp32
  const float* cap = (const float*)d_in[1];   // [32][40][1024] fp32
  const float* Wl  = (const float*)d_in[2];   // [2048][1024] fp32
  const float* bl  = (const float*)d_in[3];   // [1024] fp32
  const float* Wg  = (const float*)d_in[4];
  const float* bg  = (const float*)d_in[5];
  float* out = (float*)d_out;                 // [32][32] fp32

  char* ws = (char*)d_ws;                 // total 186,393,856 B
  float* cnrm = (float*)ws;               ws += 5120;
  float* sim1 = (float*)ws;               ws += 4096;
  u16*   WTl  = (u16*)ws;                 ws += (size_t)1024 * 2048 * 2;   // 4.2 MB
  u16*   WTg  = (u16*)ws;                 ws += (size_t)1024 * 2048 * 2;   // 4.2 MB
  u16*   preL = (u16*)ws;                 ws += (size_t)1280 * 1024 * 2;   // 2.6 MB
  u16*   preG = (u16*)ws;                 ws += (size_t)1280 * 1024 * 2;   // 2.6 MB
  u16*   imgb = (u16*)ws;                 ws += (size_t)1152 * 1024 * 2;   // 2.4 MB
  u16*   ctxT = (u16*)ws;                 ws += (size_t)32 * 1024 * 40 * 2 + 256;
  u16*   wc1  = (u16*)ws;                 ws += (size_t)40960 * 1024 * 2;  // 83.9 MB
  u16*   q2   = (u16*)ws;                 ws += (size_t)40960 * 1024 * 2;  // 83.9 MB
  u16*   capb = q2;  // alias: capb dead before gemm_dual1 writes q2

  cvt_k<<<1152, 256, 0, stream>>>(img, imgb);
  cvt_k<<<1280, 256, 0, stream>>>(cap, capb);
  ctxt_k<<<128, 256, 0, stream>>>(img, ctxT);
  transpose_k<<<dim3(64, 32, 2), dim3(32, 8), 0, stream>>>(Wl, Wg, WTl, WTg);
  capnorm_k<<<320, 256, 0, stream>>>(cap, cnrm);
  gemm_pre<<<80, 256, 0, stream>>>(cap, WTl, WTg, preL, preG);
  attn_k<1><<<1024, 256, 0, stream>>>(imgb, capb, q2, ctxT, cap, wc1, cnrm, sim1, out);
  gemm_dual1<<<2560, 256, 0, stream>>>(wc1, WTl, WTg, preL, preG, cap, bl, bg, q2);
  attn_k<2><<<1024, 256, 0, stream>>>(imgb, capb, q2, ctxT, cap, wc1, cnrm, sim1, out);
}

// Round 8
// 548.069 us; speedup vs baseline: 1.3661x; 1.0644x over previous
//
#include <hip/hip_runtime.h>
#include <stdint.h>

// C=32 captions, I=32 images, T=40 words, R=36 regions, D=1024.
// Inputs fp32; output score [32,32] fp32.
// R8: gemm_dual1 staging -> global_load_lds width-16 (no VGPR round-trip)
// + XCD swizzle (8 bn-blocks of one bm land consecutively on one XCD -> A-tile
// L2 reuse). gemm_pre reads pre-converted capb + async staging.

typedef unsigned short u16;
typedef __attribute__((ext_vector_type(8))) short bf16x8;
typedef __attribute__((ext_vector_type(4))) float f32x4;

#define MFMA_BF16(a, b, c) __builtin_amdgcn_mfma_f32_16x16x32_bf16((a), (b), (c), 0, 0, 0)

__device__ __forceinline__ float bf2f(u16 u) {
  union { unsigned v; float f; } x; x.v = ((unsigned)u) << 16; return x.f;
}
__device__ __forceinline__ u16 f2bf(float f) {  // round-to-nearest-even
  union { float f; unsigned v; } x; x.f = f;
  return (u16)((x.v + 0x7fffu + ((x.v >> 16) & 1u)) >> 16);
}
// async 16B global->LDS (DMA; LDS dest = wave-uniform base + lane*16)
__device__ __forceinline__ void gl2lds16(const u16* g, u16* l) {
  __builtin_amdgcn_global_load_lds((const __attribute__((address_space(1))) void*)g,
                                   (__attribute__((address_space(3))) void*)l, 16, 0, 0);
}

// ---------------------------------------------------------------------------
// fp32 -> bf16 convert, 4 elems/thread (n = grid*1024).
__global__ void cvt_k(const float* __restrict__ src, u16* __restrict__ dst) {
  const int idx = (blockIdx.x * 256 + threadIdx.x) * 4;
  const float4 v = *(const float4*)(src + idx);
  u16 o[4] = {f2bf(v.x), f2bf(v.y), f2bf(v.z), f2bf(v.w)};
  *(uint2*)(dst + idx) = *(const uint2*)o;
}

// ---------------------------------------------------------------------------
// Build ctxT[i][d][40] bf16 from img fp32 [i][r][d]; r pad 36..39 = 0.
__global__ void ctxt_k(const float* __restrict__ img, u16* __restrict__ ctxT) {
  const int g = blockIdx.x * 256 + threadIdx.x;  // 32768 = 32 i * 1024 d
  const int i = g >> 10, d = g & 1023;
  u16 row[40];
#pragma unroll
  for (int r = 0; r < 36; ++r) row[r] = f2bf(img[((size_t)(i * 36 + r) << 10) + d]);
#pragma unroll
  for (int r = 36; r < 40; ++r) row[r] = 0;
  u16* dst = ctxT + (size_t)g * 40;
#pragma unroll
  for (int j = 0; j < 5; ++j) *(uint4*)(dst + j * 8) = *(const uint4*)(row + j * 8);
}

// ---------------------------------------------------------------------------
// capnorm[c*40+t] = ||cap[c,t,:]|| (fp32 input)
__global__ void capnorm_k(const float* __restrict__ cap, float* __restrict__ cnorm) {
  const int wv = threadIdx.x >> 6, lane = threadIdx.x & 63;
  const int row = blockIdx.x * 4 + wv;  // < 1280
  const float* p = cap + ((size_t)row << 10) + lane * 16;
  float s = 0.f;
#pragma unroll
  for (int e = 0; e < 16; ++e) { float v = p[e]; s += v * v; }
#pragma unroll
  for (int off = 32; off > 0; off >>= 1) s += __shfl_down(s, off, 64);
  if (lane == 0) cnorm[row] = sqrtf(s);
}

// ---------------------------------------------------------------------------
// Transpose+convert W fp32 [2048][1024] -> WT bf16 [1024][2048].
__global__ void transpose_k(const float* __restrict__ Wl, const float* __restrict__ Wg,
                            u16* __restrict__ WTl, u16* __restrict__ WTg) {
  __shared__ u16 tile[32][33];
  const float* src = blockIdx.z ? Wg : Wl;
  u16* dst = blockIdx.z ? WTg : WTl;
  const int k0 = blockIdx.x * 32, n0 = blockIdx.y * 32;
  const int tx = threadIdx.x, ty = threadIdx.y;
#pragma unroll
  for (int j = 0; j < 4; ++j)
    tile[ty + 8 * j][tx] = f2bf(src[(size_t)(k0 + ty + 8 * j) * 1024 + n0 + tx]);
  __syncthreads();
#pragma unroll
  for (int j = 0; j < 4; ++j)
    dst[(size_t)(n0 + ty + 8 * j) * 2048 + k0 + tx] = tile[tx][ty + 8 * j];
}

// ---------------------------------------------------------------------------
// Pre-GEMM: pre{L,G}[ct,n] = sum_k capb[ct,k]*W{l,g}[k][n], K=1024, bf16 out.
// All staging via global_load_lds width-16. Grid 80.
__global__ __launch_bounds__(256, 2) void gemm_pre(
    const u16* __restrict__ capb, const u16* __restrict__ WTl,
    const u16* __restrict__ WTg, u16* __restrict__ outL, u16* __restrict__ outG) {
  __shared__ __align__(16) u16 lsA[128 * 32];
  __shared__ __align__(16) u16 lsBl[128 * 32];
  __shared__ __align__(16) u16 lsBg[128 * 32];
  const int tid = threadIdx.x;
  const int bm = blockIdx.x >> 3, bn = blockIdx.x & 7;
  const int wv = tid >> 6, lane = tid & 63;
  const int quad = lane >> 4, l15 = lane & 15;
  const int wm = (wv & 1) << 6, wn = (wv >> 1) << 6;

  f32x4 accL[4][4], accG[4][4];
#pragma unroll
  for (int a = 0; a < 4; ++a)
#pragma unroll
    for (int b = 0; b < 4; ++b) {
      accL[a][b] = (f32x4){0.f, 0.f, 0.f, 0.f};
      accG[a][b] = (f32x4){0.f, 0.f, 0.f, 0.f};
    }

  const size_t arow0 = (size_t)bm * 128 * 1024;
  for (int kt = 0; kt < 32; ++kt) {
    if (kt) __syncthreads();
#pragma unroll
    for (int s = 0; s < 2; ++s) {
      const int idx = s * 256 + tid;
      const int row = idx >> 2, c8 = idx & 3;
      u16* ldsb = lsA + (size_t)(s * 256 + wv * 64) * 8;  // lane-linear 16B slots
      gl2lds16(capb + arow0 + (size_t)row * 1024 + kt * 32 + c8 * 8, ldsb);
      const size_t bro = (size_t)(bn * 128 + row) * 2048 + kt * 32 + c8 * 8;
      gl2lds16(WTl + bro, lsBl + (size_t)(s * 256 + wv * 64) * 8);
      gl2lds16(WTg + bro, lsBg + (size_t)(s * 256 + wv * 64) * 8);
    }
    __syncthreads();
    bf16x8 af[4], bl8[4], bg8[4];
#pragma unroll
    for (int mt = 0; mt < 4; ++mt)
      af[mt] = *(const bf16x8*)(lsA + (wm + mt * 16 + l15) * 32 + quad * 8);
#pragma unroll
    for (int nt = 0; nt < 4; ++nt) {
      bl8[nt] = *(const bf16x8*)(lsBl + (wn + nt * 16 + l15) * 32 + quad * 8);
      bg8[nt] = *(const bf16x8*)(lsBg + (wn + nt * 16 + l15) * 32 + quad * 8);
    }
#pragma unroll
    for (int mt = 0; mt < 4; ++mt)
#pragma unroll
      for (int nt = 0; nt < 4; ++nt) {
        accL[mt][nt] = MFMA_BF16(af[mt], bl8[nt], accL[mt][nt]);
        accG[mt][nt] = MFMA_BF16(af[mt], bg8[nt], accG[mt][nt]);
      }
  }
#pragma unroll
  for (int mt = 0; mt < 4; ++mt)
#pragma unroll
    for (int nt = 0; nt < 4; ++nt)
#pragma unroll
      for (int r = 0; r < 4; ++r) {
        const int m = bm * 128 + wm + mt * 16 + quad * 4 + r;
        const int n = bn * 128 + wn + nt * 16 + l15;
        outL[(size_t)m * 1024 + n] = f2bf(accL[mt][nt][r]);
        outG[(size_t)m * 1024 + n] = f2bf(accG[mt][nt][r]);
      }
}

// ---------------------------------------------------------------------------
// Gated-memory GEMM: q2 = cap*g + tanh(wc1@Wb + pre + b)*(1-g). Grid 2560.
// XCD swizzle: bm = (blk>>6)*8 + (blk&7), bn = (blk>>3)&7 -> the 8 bn-blocks of
// one bm are consecutive on one XCD (indices = x mod 8) -> A-tile L2 reuse.
// Staging via global_load_lds width-16.
__global__ __launch_bounds__(256, 2) void gemm_dual1(
    const u16* __restrict__ A, const u16* __restrict__ WTl, const u16* __restrict__ WTg,
    const u16* __restrict__ preL, const u16* __restrict__ preG,
    const float* __restrict__ capf, const float* __restrict__ bL,
    const float* __restrict__ bG, u16* __restrict__ q2) {
  __shared__ __align__(16) u16 lsA[128 * 32];
  __shared__ __align__(16) u16 lsBl[128 * 32];
  __shared__ __align__(16) u16 lsBg[128 * 32];
  const int tid = threadIdx.x;
  const int bm = ((int)blockIdx.x >> 6) * 8 + ((int)blockIdx.x & 7);
  const int bn = ((int)blockIdx.x >> 3) & 7;
  const int wv = tid >> 6, lane = tid & 63;
  const int quad = lane >> 4, l15 = lane & 15;
  const int wm = (wv & 1) << 6, wn = (wv >> 1) << 6;

  f32x4 accL[4][4], accG[4][4];
#pragma unroll
  for (int a = 0; a < 4; ++a)
#pragma unroll
    for (int b = 0; b < 4; ++b) {
      accL[a][b] = (f32x4){0.f, 0.f, 0.f, 0.f};
      accG[a][b] = (f32x4){0.f, 0.f, 0.f, 0.f};
    }

  const size_t arow0 = (size_t)bm * 128 * 1024;
  for (int kt = 0; kt < 32; ++kt) {
    if (kt) __syncthreads();
#pragma unroll
    for (int s = 0; s < 2; ++s) {
      const int idx = s * 256 + tid;
      const int row = idx >> 2, c8 = idx & 3;
      gl2lds16(A + arow0 + (size_t)row * 1024 + kt * 32 + c8 * 8,
               lsA + (size_t)(s * 256 + wv * 64) * 8);
      const size_t bro = (size_t)(bn * 128 + row) * 2048 + 1024 + kt * 32 + c8 * 8;
      gl2lds16(WTl + bro, lsBl + (size_t)(s * 256 + wv * 64) * 8);
      gl2lds16(WTg + bro, lsBg + (size_t)(s * 256 + wv * 64) * 8);
    }
    __syncthreads();
    bf16x8 af[4], bl8[4], bg8[4];
#pragma unroll
    for (int mt = 0; mt < 4; ++mt)
      af[mt] = *(const bf16x8*)(lsA + (wm + mt * 16 + l15) * 32 + quad * 8);
#pragma unroll
    for (int nt = 0; nt < 4; ++nt) {
      bl8[nt] = *(const bf16x8*)(lsBl + (wn + nt * 16 + l15) * 32 + quad * 8);
      bg8[nt] = *(const bf16x8*)(lsBg + (wn + nt * 16 + l15) * 32 + quad * 8);
    }
#pragma unroll
    for (int mt = 0; mt < 4; ++mt)
#pragma unroll
      for (int nt = 0; nt < 4; ++nt) {
        accL[mt][nt] = MFMA_BF16(af[mt], bl8[nt], accL[mt][nt]);
        accG[mt][nt] = MFMA_BF16(af[mt], bg8[nt], accG[mt][nt]);
      }
  }
#pragma unroll
  for (int mt = 0; mt < 4; ++mt)
#pragma unroll
    for (int nt = 0; nt < 4; ++nt)
#pragma unroll
      for (int r = 0; r < 4; ++r) {
        const int m = bm * 128 + wm + mt * 16 + quad * 4 + r;
        const int n = bn * 128 + wn + nt * 16 + l15;
        const int c = m / 1280;            // m = (c*32+i)*40 + t
        const int t = (m - c * 1280) % 40;
        const int ct = c * 40 + t;
        const float aL = accL[mt][nt][r] + bf2f(preL[(size_t)ct * 1024 + n]) + bL[n];
        const float aG = accG[mt][nt][r] + bf2f(preG[(size_t)ct * 1024 + n]) + bG[n];
        const float g = 1.f / (1.f + __expf(-aG));
        const float u = 2.f / (1.f + __expf(-2.f * aL)) - 1.f;  // tanh
        const float cv = capf[(size_t)ct * 1024 + n];
        q2[(size_t)m * 1024 + n] = f2bf(cv * g + u * (1.f - g));
      }
}

// ---------------------------------------------------------------------------
// Barrier-free fused attention (R7 structure, unchanged).
template <int ITER>
__global__ __launch_bounds__(256, 2) void attn_k(
    const u16* __restrict__ imgb, const u16* __restrict__ capb,
    const u16* __restrict__ q2, const u16* __restrict__ ctxT,
    const float* __restrict__ capf, u16* __restrict__ wc1,
    const float* __restrict__ cnorm, float* __restrict__ sim1,
    float* __restrict__ score) {
  __shared__ __align__(16) u16 lsAT[4][48 * 72];
  __shared__ float lsCOS[48], lsWN[48], lsRED[48];

  const int tid = threadIdx.x;
  const int c = blockIdx.x >> 5, i = blockIdx.x & 31;
  const int pair = c * 32 + i;
  const int wv = tid >> 6, lane = tid & 63;
  const int quad = lane >> 4, l15 = lane & 15;

  {
    unsigned* z = (unsigned*)lsAT[wv];
    for (int k = lane; k < 1728; k += 64) z[k] = 0u;
    if (tid < 48) { lsCOS[tid] = 0.f; lsWN[tid] = 0.f; }
  }

  const u16* arow[3]; bool avalid[3];
  const u16* brow[3]; bool bvalid[3];
#pragma unroll
  for (int mt = 0; mt < 3; ++mt) {
    const int r = mt * 16 + l15;
    avalid[mt] = r < 36;
    arow[mt] = imgb + ((size_t)(i * 36 + (r < 36 ? r : 35)) << 10);
  }
#pragma unroll
  for (int nt = 0; nt < 3; ++nt) {
    const int t = nt * 16 + l15;
    bvalid[nt] = t < 40;
    const int tc = t < 40 ? t : 39;
    brow[nt] = (ITER == 1) ? (capb + ((size_t)(c * 40 + tc) << 10))
                           : (q2 + ((size_t)(pair * 40 + tc) << 10));
  }
  const bf16x8 zero8 = {0, 0, 0, 0, 0, 0, 0, 0};

  f32x4 accS[3][3];
#pragma unroll
  for (int a = 0; a < 3; ++a)
#pragma unroll
    for (int b = 0; b < 3; ++b) accS[a][b] = (f32x4){0.f, 0.f, 0.f, 0.f};

  for (int kk = 0; kk < 32; ++kk) {
    const int ko = kk * 32 + quad * 8;
    bf16x8 af[3], bq[3];
#pragma unroll
    for (int mt = 0; mt < 3; ++mt)
      af[mt] = avalid[mt] ? *(const bf16x8*)(arow[mt] + ko) : zero8;
#pragma unroll
    for (int nt = 0; nt < 3; ++nt)
      bq[nt] = bvalid[nt] ? *(const bf16x8*)(brow[nt] + ko) : zero8;
#pragma unroll
    for (int mt = 0; mt < 3; ++mt)
#pragma unroll
      for (int nt = 0; nt < 3; ++nt)
        accS[mt][nt] = MFMA_BF16(af[mt], bq[nt], accS[mt][nt]);
  }

  float rn[3][4];
#pragma unroll
  for (int mt = 0; mt < 3; ++mt)
#pragma unroll
    for (int rg = 0; rg < 4; ++rg) {
      float s2 = 0.f;
#pragma unroll
      for (int nt = 0; nt < 3; ++nt) {
        float v = accS[mt][nt][rg]; v = v > 0.f ? v : 0.1f * v; s2 += v * v;
      }
      s2 += __shfl_xor(s2, 1, 64); s2 += __shfl_xor(s2, 2, 64);
      s2 += __shfl_xor(s2, 4, 64); s2 += __shfl_xor(s2, 8, 64);
      rn[mt][rg] = sqrtf(s2) + 1e-8f;
    }
  float mx[3] = {-3.0e38f, -3.0e38f, -3.0e38f};
#pragma unroll
  for (int mt = 0; mt < 3; ++mt)
#pragma unroll
    for (int nt = 0; nt < 3; ++nt)
#pragma unroll
      for (int rg = 0; rg < 4; ++rg) {
        const int r = mt * 16 + quad * 4 + rg;
        float v = accS[mt][nt][rg]; v = v > 0.f ? v : 0.1f * v;
        float zz = 9.f * v / rn[mt][rg];
        zz = (r < 36) ? zz : -3.0e38f;
        accS[mt][nt][rg] = zz;
        mx[nt] = fmaxf(mx[nt], zz);
      }
#pragma unroll
  for (int nt = 0; nt < 3; ++nt) {
    mx[nt] = fmaxf(mx[nt], __shfl_xor(mx[nt], 16, 64));
    mx[nt] = fmaxf(mx[nt], __shfl_xor(mx[nt], 32, 64));
  }
  float ss[3] = {0.f, 0.f, 0.f};
#pragma unroll
  for (int mt = 0; mt < 3; ++mt)
#pragma unroll
    for (int nt = 0; nt < 3; ++nt)
#pragma unroll
      for (int rg = 0; rg < 4; ++rg) {
        const float e = __expf(accS[mt][nt][rg] - mx[nt]);
        accS[mt][nt][rg] = e; ss[nt] += e;
      }
#pragma unroll
  for (int nt = 0; nt < 3; ++nt) {
    ss[nt] += __shfl_xor(ss[nt], 16, 64);
    ss[nt] += __shfl_xor(ss[nt], 32, 64);
    ss[nt] = 1.f / ss[nt];
  }
#pragma unroll
  for (int nt = 0; nt < 3; ++nt) {
    const int t = nt * 16 + l15;
    if (t < 40) {
#pragma unroll
      for (int mt = 0; mt < 3; ++mt)
#pragma unroll
        for (int rg = 0; rg < 4; ++rg)
          lsAT[wv][t * 72 + mt * 16 + quad * 4 + rg] = f2bf(accS[mt][nt][rg] * ss[nt]);
    }
  }

  bf16x8 afA[3][2];
#pragma unroll
  for (int mt2 = 0; mt2 < 3; ++mt2)
#pragma unroll
    for (int ks = 0; ks < 2; ++ks)
      afA[mt2][ks] = *(const bf16x8*)(lsAT[wv] + (mt2 * 16 + l15) * 72 + ks * 32 + quad * 8);

  float pn[12], pw[12];
#pragma unroll
  for (int k = 0; k < 12; ++k) { pn[k] = 0.f; pw[k] = 0.f; }

  const int dbase = wv * 256;
  for (int nt2 = 0; nt2 < 16; ++nt2) {
    const int d = dbase + nt2 * 16 + l15;
    const u16* bp = ctxT + ((size_t)(i << 10) + d) * 40;
    const bf16x8 b0 = *(const bf16x8*)(bp + quad * 8);
    const bf16x8 b1 = *(const bf16x8*)(bp + 32 + quad * 8);
    f32x4 acc[3];
#pragma unroll
    for (int mt2 = 0; mt2 < 3; ++mt2) {
      acc[mt2] = (f32x4){0.f, 0.f, 0.f, 0.f};
      acc[mt2] = MFMA_BF16(afA[mt2][0], b0, acc[mt2]);
      acc[mt2] = MFMA_BF16(afA[mt2][1], b1, acc[mt2]);
    }
#pragma unroll
    for (int mt2 = 0; mt2 < 3; ++mt2)
#pragma unroll
      for (int rg = 0; rg < 4; ++rg) {
        const int t = mt2 * 16 + quad * 4 + rg;
        if (t < 40) {
          const float w = acc[mt2][rg];
          const float cv = capf[((size_t)(c * 40 + t) << 10) + d];
          pn[mt2 * 4 + rg] += cv * w;
          pw[mt2 * 4 + rg] += w * w;
          if (ITER == 1) wc1[(((size_t)pair * 40 + t) << 10) + d] = f2bf(w);
        }
      }
  }
#pragma unroll
  for (int k = 0; k < 12; ++k) {
#pragma unroll
    for (int off = 1; off <= 8; off <<= 1) {
      pn[k] += __shfl_xor(pn[k], off, 64);
      pw[k] += __shfl_xor(pw[k], off, 64);
    }
  }
  __syncthreads();
  if (l15 == 0) {
#pragma unroll
    for (int mt2 = 0; mt2 < 3; ++mt2)
#pragma unroll
      for (int rg = 0; rg < 4; ++rg) {
        const int t = mt2 * 16 + quad * 4 + rg;
        if (t < 40) {
          atomicAdd(&lsCOS[t], pn[mt2 * 4 + rg]);
          atomicAdd(&lsWN[t], pw[mt2 * 4 + rg]);
        }
      }
  }
  __syncthreads();
  if (tid < 40) {
    const float w2 = sqrtf(lsWN[tid]);
    lsRED[tid] = lsCOS[tid] / fmaxf(cnorm[c * 40 + tid] * w2, 1e-8f);
  }
  __syncthreads();
  if (tid == 0) {
    float s = 0.f;
    for (int t = 0; t < 40; ++t) s += lsRED[t];
    s *= (1.f / 40.f);
    if (ITER == 1) sim1[pair] = s;
    else score[i * 32 + c] = s + sim1[pair];
  }
}

// ---------------------------------------------------------------------------
extern "C" void kernel_launch(void* const* d_in, const int* in_sizes, int n_in,
                              void* d_out, int out_size, void* d_ws, size_t ws_size,
                              hipStream_t stream) {
  const float* img = (const float*)d_in[0];   // [32][36][1024] fp32
  const float* cap = (const float*)d_in[1];   // [32][40][1024] fp32
  const float* Wl  = (const float*)d_in[2];   // [2048][1024] fp32
  const float* bl  = (const float*)d_in[3];   // [1024] fp32
  const float* Wg  = (const float*)d_in[4];
  const float* bg  = (const float*)d_in[5];
  float* out = (float*)d_out;                 // [32][32] fp32

  char* ws = (char*)d_ws;                 // total 186,393,856 B
  float* cnrm = (float*)ws;               ws += 5120;
  float* sim1 = (float*)ws;               ws += 4096;
  u16*   WTl  = (u16*)ws;                 ws += (size_t)1024 * 2048 * 2;   // 4.2 MB
  u16*   WTg  = (u16*)ws;                 ws += (size_t)1024 * 2048 * 2;   // 4.2 MB
  u16*   preL = (u16*)ws;                 ws += (size_t)1280 * 1024 * 2;   // 2.6 MB
  u16*   preG = (u16*)ws;                 ws += (size_t)1280 * 1024 * 2;   // 2.6 MB
  u16*   imgb = (u16*)ws;                 ws += (size_t)1152 * 1024 * 2;   // 2.4 MB
  u16*   ctxT = (u16*)ws;                 ws += (size_t)32 * 1024 * 40 * 2 + 256;
  u16*   wc1  = (u16*)ws;                 ws += (size_t)40960 * 1024 * 2;  // 83.9 MB
  u16*   q2   = (u16*)ws;                 ws += (size_t)40960 * 1024 * 2;  // 83.9 MB
  u16*   capb = q2;  // alias: capb dead before gemm_dual1 writes q2

  cvt_k<<<1152, 256, 0, stream>>>(img, imgb);
  cvt_k<<<1280, 256, 0, stream>>>(cap, capb);
  ctxt_k<<<128, 256, 0, stream>>>(img, ctxT);
  transpose_k<<<dim3(64, 32, 2), dim3(32, 8), 0, stream>>>(Wl, Wg, WTl, WTg);
  capnorm_k<<<320, 256, 0, stream>>>(cap, cnrm);
  gemm_pre<<<80, 256, 0, stream>>>(capb, WTl, WTg, preL, preG);
  attn_k<1><<<1024, 256, 0, stream>>>(imgb, capb, q2, ctxT, cap, wc1, cnrm, sim1, out);
  gemm_dual1<<<2560, 256, 0, stream>>>(wc1, WTl, WTg, preL, preG, cap, bl, bg, q2);
  attn_k<2><<<1024, 256, 0, stream>>>(imgb, capb, q2, ctxT, cap, wc1, cnrm, sim1, out);
}

// Round 9
// 500.597 us; speedup vs baseline: 1.4956x; 1.0948x over previous
//
#include <hip/hip_runtime.h>
#include <stdint.h>

// C=32 captions, I=32 images, T=40 words, R=36 regions, D=1024.
// Inputs fp32; output score [32,32] fp32.
// R9: wc1/q2 stored as [(c*40+t)*32+i][d] -> gemm_dual1 epilogue operands
// become per-block tiles staged in LDS (no scattered loads, no int div).
// BK=64 (half the barriers) + XOR-swizzled LDS staging (bank-conflict-free
// frag reads, DMA stays lane-linear).

typedef unsigned short u16;
typedef __attribute__((ext_vector_type(8))) short bf16x8;
typedef __attribute__((ext_vector_type(4))) float f32x4;

#define MFMA_BF16(a, b, c) __builtin_amdgcn_mfma_f32_16x16x32_bf16((a), (b), (c), 0, 0, 0)

__device__ __forceinline__ float bf2f(u16 u) {
  union { unsigned v; float f; } x; x.v = ((unsigned)u) << 16; return x.f;
}
__device__ __forceinline__ u16 f2bf(float f) {  // round-to-nearest-even
  union { float f; unsigned v; } x; x.f = f;
  return (u16)((x.v + 0x7fffu + ((x.v >> 16) & 1u)) >> 16);
}
// async 16B global->LDS (DMA; LDS dest = wave-uniform base + lane*16)
__device__ __forceinline__ void gl2lds16(const u16* g, u16* l) {
  __builtin_amdgcn_global_load_lds((const __attribute__((address_space(1))) void*)g,
                                   (__attribute__((address_space(3))) void*)l, 16, 0, 0);
}

// ---------------------------------------------------------------------------
__global__ void cvt_k(const float* __restrict__ src, u16* __restrict__ dst) {
  const int idx = (blockIdx.x * 256 + threadIdx.x) * 4;
  const float4 v = *(const float4*)(src + idx);
  u16 o[4] = {f2bf(v.x), f2bf(v.y), f2bf(v.z), f2bf(v.w)};
  *(uint2*)(dst + idx) = *(const uint2*)o;
}

// ---------------------------------------------------------------------------
// Build ctxT[i][d][40] bf16 from img fp32 [i][r][d]; r pad 36..39 = 0.
__global__ void ctxt_k(const float* __restrict__ img, u16* __restrict__ ctxT) {
  const int g = blockIdx.x * 256 + threadIdx.x;  // 32768 = 32 i * 1024 d
  const int i = g >> 10, d = g & 1023;
  u16 row[40];
#pragma unroll
  for (int r = 0; r < 36; ++r) row[r] = f2bf(img[((size_t)(i * 36 + r) << 10) + d]);
#pragma unroll
  for (int r = 36; r < 40; ++r) row[r] = 0;
  u16* dst = ctxT + (size_t)g * 40;
#pragma unroll
  for (int j = 0; j < 5; ++j) *(uint4*)(dst + j * 8) = *(const uint4*)(row + j * 8);
}

// ---------------------------------------------------------------------------
__global__ void capnorm_k(const float* __restrict__ cap, float* __restrict__ cnorm) {
  const int wv = threadIdx.x >> 6, lane = threadIdx.x & 63;
  const int row = blockIdx.x * 4 + wv;  // < 1280
  const float* p = cap + ((size_t)row << 10) + lane * 16;
  float s = 0.f;
#pragma unroll
  for (int e = 0; e < 16; ++e) { float v = p[e]; s += v * v; }
#pragma unroll
  for (int off = 32; off > 0; off >>= 1) s += __shfl_down(s, off, 64);
  if (lane == 0) cnorm[row] = sqrtf(s);
}

// ---------------------------------------------------------------------------
__global__ void transpose_k(const float* __restrict__ Wl, const float* __restrict__ Wg,
                            u16* __restrict__ WTl, u16* __restrict__ WTg) {
  __shared__ u16 tile[32][33];
  const float* src = blockIdx.z ? Wg : Wl;
  u16* dst = blockIdx.z ? WTg : WTl;
  const int k0 = blockIdx.x * 32, n0 = blockIdx.y * 32;
  const int tx = threadIdx.x, ty = threadIdx.y;
#pragma unroll
  for (int j = 0; j < 4; ++j)
    tile[ty + 8 * j][tx] = f2bf(src[(size_t)(k0 + ty + 8 * j) * 1024 + n0 + tx]);
  __syncthreads();
#pragma unroll
  for (int j = 0; j < 4; ++j)
    dst[(size_t)(n0 + ty + 8 * j) * 2048 + k0 + tx] = tile[tx][ty + 8 * j];
}

// ---------------------------------------------------------------------------
// Pre-GEMM: pre{L,G}[ct,n] = sum_k capb[ct,k]*W{l,g}[k][n], K=1024, bf16 out.
__global__ __launch_bounds__(256, 2) void gemm_pre(
    const u16* __restrict__ capb, const u16* __restrict__ WTl,
    const u16* __restrict__ WTg, u16* __restrict__ outL, u16* __restrict__ outG) {
  __shared__ __align__(16) u16 lsA[128 * 32];
  __shared__ __align__(16) u16 lsBl[128 * 32];
  __shared__ __align__(16) u16 lsBg[128 * 32];
  const int tid = threadIdx.x;
  const int bm = blockIdx.x >> 3, bn = blockIdx.x & 7;
  const int wv = tid >> 6, lane = tid & 63;
  const int quad = lane >> 4, l15 = lane & 15;
  const int wm = (wv & 1) << 6, wn = (wv >> 1) << 6;

  f32x4 accL[4][4], accG[4][4];
#pragma unroll
  for (int a = 0; a < 4; ++a)
#pragma unroll
    for (int b = 0; b < 4; ++b) {
      accL[a][b] = (f32x4){0.f, 0.f, 0.f, 0.f};
      accG[a][b] = (f32x4){0.f, 0.f, 0.f, 0.f};
    }

  const size_t arow0 = (size_t)bm * 128 * 1024;
  for (int kt = 0; kt < 32; ++kt) {
    if (kt) __syncthreads();
#pragma unroll
    for (int s = 0; s < 2; ++s) {
      const int idx = s * 256 + tid;
      const int row = idx >> 2, c8 = idx & 3;
      gl2lds16(capb + arow0 + (size_t)row * 1024 + kt * 32 + c8 * 8,
               lsA + (size_t)(s * 256 + wv * 64) * 8);
      const size_t bro = (size_t)(bn * 128 + row) * 2048 + kt * 32 + c8 * 8;
      gl2lds16(WTl + bro, lsBl + (size_t)(s * 256 + wv * 64) * 8);
      gl2lds16(WTg + bro, lsBg + (size_t)(s * 256 + wv * 64) * 8);
    }
    __syncthreads();
    bf16x8 af[4], bl8[4], bg8[4];
#pragma unroll
    for (int mt = 0; mt < 4; ++mt)
      af[mt] = *(const bf16x8*)(lsA + (wm + mt * 16 + l15) * 32 + quad * 8);
#pragma unroll
    for (int nt = 0; nt < 4; ++nt) {
      bl8[nt] = *(const bf16x8*)(lsBl + (wn + nt * 16 + l15) * 32 + quad * 8);
      bg8[nt] = *(const bf16x8*)(lsBg + (wn + nt * 16 + l15) * 32 + quad * 8);
    }
#pragma unroll
    for (int mt = 0; mt < 4; ++mt)
#pragma unroll
      for (int nt = 0; nt < 4; ++nt) {
        accL[mt][nt] = MFMA_BF16(af[mt], bl8[nt], accL[mt][nt]);
        accG[mt][nt] = MFMA_BF16(af[mt], bg8[nt], accG[mt][nt]);
      }
  }
#pragma unroll
  for (int mt = 0; mt < 4; ++mt)
#pragma unroll
    for (int nt = 0; nt < 4; ++nt)
#pragma unroll
      for (int r = 0; r < 4; ++r) {
        const int m = bm * 128 + wm + mt * 16 + quad * 4 + r;
        const int n = bn * 128 + wn + nt * 16 + l15;
        outL[(size_t)m * 1024 + n] = f2bf(accL[mt][nt][r]);
        outG[(size_t)m * 1024 + n] = f2bf(accG[mt][nt][r]);
      }
}

// ---------------------------------------------------------------------------
// Gated-memory GEMM over reordered rows m = (c*40+t)*32+i = ct*32+i.
// BK=64, XOR-swizzled LDS staging, per-block epilogue tiles in LDS.
// q2 = cap*g + tanh(wc1@Wb + pre + b)*(1-g). Grid 2560, XCD swizzle.
__global__ __launch_bounds__(256, 2) void gemm_dual1(
    const u16* __restrict__ A, const u16* __restrict__ WTl, const u16* __restrict__ WTg,
    const u16* __restrict__ preL, const u16* __restrict__ preG,
    const float* __restrict__ capf, const float* __restrict__ bL,
    const float* __restrict__ bG, u16* __restrict__ q2) {
  __shared__ __align__(16) u16 lsA[128 * 64];
  __shared__ __align__(16) u16 lsBl[128 * 64];
  __shared__ __align__(16) u16 lsBg[128 * 64];
  __shared__ u16 preLs[512], preGs[512];     // [ctl][nl] ctl<4, nl<128
  __shared__ float capfs[512], bLs[128], bGs[128];
  const int tid = threadIdx.x;
  const int bm = ((int)blockIdx.x >> 6) * 8 + ((int)blockIdx.x & 7);
  const int bn = ((int)blockIdx.x >> 3) & 7;
  const int wv = tid >> 6, lane = tid & 63;
  const int quad = lane >> 4, l15 = lane & 15;
  const int wm = (wv & 1) << 6, wn = (wv >> 1) << 6;

  // ---- stage epilogue tiles once (block covers ct in [bm*4, bm*4+4))
  for (int idx = tid; idx < 512; idx += 256) {
    const int j = idx >> 7, nl = idx & 127;
    const size_t g = (size_t)(bm * 4 + j) * 1024 + bn * 128 + nl;
    preLs[idx] = preL[g];
    preGs[idx] = preG[g];
    capfs[idx] = capf[g];
  }
  if (tid < 128) { bLs[tid] = bL[bn * 128 + tid]; bGs[tid] = bG[bn * 128 + tid]; }

  f32x4 accL[4][4], accG[4][4];
#pragma unroll
  for (int a = 0; a < 4; ++a)
#pragma unroll
    for (int b = 0; b < 4; ++b) {
      accL[a][b] = (f32x4){0.f, 0.f, 0.f, 0.f};
      accG[a][b] = (f32x4){0.f, 0.f, 0.f, 0.f};
    }

  const size_t arow0 = (size_t)bm * 128 * 1024;
  for (int kt = 0; kt < 16; ++kt) {
    if (kt) __syncthreads();
#pragma unroll
    for (int s = 0; s < 4; ++s) {
      const int idx = s * 256 + tid;           // slot = row*8 + c8dst
      const int row = idx >> 3, c8d = idx & 7;
      const int c8s = c8d ^ (row & 7);         // XOR bank swizzle
      u16* dA = lsA + (size_t)(s * 256 + wv * 64) * 8;   // lane-linear dest
      gl2lds16(A + arow0 + (size_t)row * 1024 + kt * 64 + c8s * 8, dA);
      const size_t bro = (size_t)(bn * 128 + row) * 2048 + 1024 + kt * 64 + c8s * 8;
      gl2lds16(WTl + bro, lsBl + (size_t)(s * 256 + wv * 64) * 8);
      gl2lds16(WTg + bro, lsBg + (size_t)(s * 256 + wv * 64) * 8);
    }
    __syncthreads();
#pragma unroll
    for (int ks = 0; ks < 2; ++ks) {
      bf16x8 af[4], bl8[4], bg8[4];
#pragma unroll
      for (int mt = 0; mt < 4; ++mt) {
        const int rr = wm + mt * 16 + l15;
        af[mt] = *(const bf16x8*)(lsA + rr * 64 + ((((ks << 2) | quad) ^ (rr & 7)) << 3));
      }
#pragma unroll
      for (int nt = 0; nt < 4; ++nt) {
        const int rb = wn + nt * 16 + l15;
        const int so = (((ks << 2) | quad) ^ (rb & 7)) << 3;
        bl8[nt] = *(const bf16x8*)(lsBl + rb * 64 + so);
        bg8[nt] = *(const bf16x8*)(lsBg + rb * 64 + so);
      }
#pragma unroll
      for (int mt = 0; mt < 4; ++mt)
#pragma unroll
        for (int nt = 0; nt < 4; ++nt) {
          accL[mt][nt] = MFMA_BF16(af[mt], bl8[nt], accL[mt][nt]);
          accG[mt][nt] = MFMA_BF16(af[mt], bg8[nt], accG[mt][nt]);
        }
    }
  }
  // ---- epilogue: all operands from LDS tiles; ct = m>>5 (no division)
#pragma unroll
  for (int mt = 0; mt < 4; ++mt)
#pragma unroll
    for (int nt = 0; nt < 4; ++nt)
#pragma unroll
      for (int r = 0; r < 4; ++r) {
        const int lm = wm + mt * 16 + quad * 4 + r;   // 0..127
        const int nl = wn + nt * 16 + l15;            // 0..127
        const int e = (lm >> 5) * 128 + nl;           // ctl*128+nl
        const float aL = accL[mt][nt][r] + bf2f(preLs[e]) + bLs[nl];
        const float aG = accG[mt][nt][r] + bf2f(preGs[e]) + bGs[nl];
        const float g = 1.f / (1.f + __expf(-aG));
        const float u = 2.f / (1.f + __expf(-2.f * aL)) - 1.f;  // tanh
        q2[(size_t)(bm * 128 + lm) * 1024 + bn * 128 + nl] =
            f2bf(capfs[e] * g + u * (1.f - g));
      }
}

// ---------------------------------------------------------------------------
// Barrier-free fused attention (R7 structure); wc1/q2 rows = (c*40+t)*32+i.
template <int ITER>
__global__ __launch_bounds__(256, 2) void attn_k(
    const u16* __restrict__ imgb, const u16* __restrict__ capb,
    const u16* __restrict__ q2, const u16* __restrict__ ctxT,
    const float* __restrict__ capf, u16* __restrict__ wc1,
    const float* __restrict__ cnorm, float* __restrict__ sim1,
    float* __restrict__ score) {
  __shared__ __align__(16) u16 lsAT[4][48 * 72];
  __shared__ float lsCOS[48], lsWN[48], lsRED[48];

  const int tid = threadIdx.x;
  const int c = blockIdx.x >> 5, i = blockIdx.x & 31;
  const int pair = c * 32 + i;
  const int wv = tid >> 6, lane = tid & 63;
  const int quad = lane >> 4, l15 = lane & 15;

  {
    unsigned* z = (unsigned*)lsAT[wv];
    for (int k = lane; k < 1728; k += 64) z[k] = 0u;
    if (tid < 48) { lsCOS[tid] = 0.f; lsWN[tid] = 0.f; }
  }

  const u16* arow[3]; bool avalid[3];
  const u16* brow[3]; bool bvalid[3];
#pragma unroll
  for (int mt = 0; mt < 3; ++mt) {
    const int r = mt * 16 + l15;
    avalid[mt] = r < 36;
    arow[mt] = imgb + ((size_t)(i * 36 + (r < 36 ? r : 35)) << 10);
  }
#pragma unroll
  for (int nt = 0; nt < 3; ++nt) {
    const int t = nt * 16 + l15;
    bvalid[nt] = t < 40;
    const int tc = t < 40 ? t : 39;
    brow[nt] = (ITER == 1) ? (capb + ((size_t)(c * 40 + tc) << 10))
                           : (q2 + ((size_t)((c * 40 + tc) * 32 + i) << 10));
  }
  const bf16x8 zero8 = {0, 0, 0, 0, 0, 0, 0, 0};

  f32x4 accS[3][3];
#pragma unroll
  for (int a = 0; a < 3; ++a)
#pragma unroll
    for (int b = 0; b < 3; ++b) accS[a][b] = (f32x4){0.f, 0.f, 0.f, 0.f};

  for (int kk = 0; kk < 32; ++kk) {
    const int ko = kk * 32 + quad * 8;
    bf16x8 af[3], bq[3];
#pragma unroll
    for (int mt = 0; mt < 3; ++mt)
      af[mt] = avalid[mt] ? *(const bf16x8*)(arow[mt] + ko) : zero8;
#pragma unroll
    for (int nt = 0; nt < 3; ++nt)
      bq[nt] = bvalid[nt] ? *(const bf16x8*)(brow[nt] + ko) : zero8;
#pragma unroll
    for (int mt = 0; mt < 3; ++mt)
#pragma unroll
      for (int nt = 0; nt < 3; ++nt)
        accS[mt][nt] = MFMA_BF16(af[mt], bq[nt], accS[mt][nt]);
  }

  float rn[3][4];
#pragma unroll
  for (int mt = 0; mt < 3; ++mt)
#pragma unroll
    for (int rg = 0; rg < 4; ++rg) {
      float s2 = 0.f;
#pragma unroll
      for (int nt = 0; nt < 3; ++nt) {
        float v = accS[mt][nt][rg]; v = v > 0.f ? v : 0.1f * v; s2 += v * v;
      }
      s2 += __shfl_xor(s2, 1, 64); s2 += __shfl_xor(s2, 2, 64);
      s2 += __shfl_xor(s2, 4, 64); s2 += __shfl_xor(s2, 8, 64);
      rn[mt][rg] = sqrtf(s2) + 1e-8f;
    }
  float mx[3] = {-3.0e38f, -3.0e38f, -3.0e38f};
#pragma unroll
  for (int mt = 0; mt < 3; ++mt)
#pragma unroll
    for (int nt = 0; nt < 3; ++nt)
#pragma unroll
      for (int rg = 0; rg < 4; ++rg) {
        const int r = mt * 16 + quad * 4 + rg;
        float v = accS[mt][nt][rg]; v = v > 0.f ? v : 0.1f * v;
        float zz = 9.f * v / rn[mt][rg];
        zz = (r < 36) ? zz : -3.0e38f;
        accS[mt][nt][rg] = zz;
        mx[nt] = fmaxf(mx[nt], zz);
      }
#pragma unroll
  for (int nt = 0; nt < 3; ++nt) {
    mx[nt] = fmaxf(mx[nt], __shfl_xor(mx[nt], 16, 64));
    mx[nt] = fmaxf(mx[nt], __shfl_xor(mx[nt], 32, 64));
  }
  float ss[3] = {0.f, 0.f, 0.f};
#pragma unroll
  for (int mt = 0; mt < 3; ++mt)
#pragma unroll
    for (int nt = 0; nt < 3; ++nt)
#pragma unroll
      for (int rg = 0; rg < 4; ++rg) {
        const float e = __expf(accS[mt][nt][rg] - mx[nt]);
        accS[mt][nt][rg] = e; ss[nt] += e;
      }
#pragma unroll
  for (int nt = 0; nt < 3; ++nt) {
    ss[nt] += __shfl_xor(ss[nt], 16, 64);
    ss[nt] += __shfl_xor(ss[nt], 32, 64);
    ss[nt] = 1.f / ss[nt];
  }
#pragma unroll
  for (int nt = 0; nt < 3; ++nt) {
    const int t = nt * 16 + l15;
    if (t < 40) {
#pragma unroll
      for (int mt = 0; mt < 3; ++mt)
#pragma unroll
        for (int rg = 0; rg < 4; ++rg)
          lsAT[wv][t * 72 + mt * 16 + quad * 4 + rg] = f2bf(accS[mt][nt][rg] * ss[nt]);
    }
  }

  bf16x8 afA[3][2];
#pragma unroll
  for (int mt2 = 0; mt2 < 3; ++mt2)
#pragma unroll
    for (int ks = 0; ks < 2; ++ks)
      afA[mt2][ks] = *(const bf16x8*)(lsAT[wv] + (mt2 * 16 + l15) * 72 + ks * 32 + quad * 8);

  float pn[12], pw[12];
#pragma unroll
  for (int k = 0; k < 12; ++k) { pn[k] = 0.f; pw[k] = 0.f; }

  const int dbase = wv * 256;
  for (int nt2 = 0; nt2 < 16; ++nt2) {
    const int d = dbase + nt2 * 16 + l15;
    const u16* bp = ctxT + ((size_t)(i << 10) + d) * 40;
    const bf16x8 b0 = *(const bf16x8*)(bp + quad * 8);
    const bf16x8 b1 = *(const bf16x8*)(bp + 32 + quad * 8);
    f32x4 acc[3];
#pragma unroll
    for (int mt2 = 0; mt2 < 3; ++mt2) {
      acc[mt2] = (f32x4){0.f, 0.f, 0.f, 0.f};
      acc[mt2] = MFMA_BF16(afA[mt2][0], b0, acc[mt2]);
      acc[mt2] = MFMA_BF16(afA[mt2][1], b1, acc[mt2]);
    }
#pragma unroll
    for (int mt2 = 0; mt2 < 3; ++mt2)
#pragma unroll
      for (int rg = 0; rg < 4; ++rg) {
        const int t = mt2 * 16 + quad * 4 + rg;
        if (t < 40) {
          const float w = acc[mt2][rg];
          const float cv = capf[((size_t)(c * 40 + t) << 10) + d];
          pn[mt2 * 4 + rg] += cv * w;
          pw[mt2 * 4 + rg] += w * w;
          if (ITER == 1)
            wc1[((size_t)((c * 40 + t) * 32 + i) << 10) + d] = f2bf(w);
        }
      }
  }
#pragma unroll
  for (int k = 0; k < 12; ++k) {
#pragma unroll
    for (int off = 1; off <= 8; off <<= 1) {
      pn[k] += __shfl_xor(pn[k], off, 64);
      pw[k] += __shfl_xor(pw[k], off, 64);
    }
  }
  __syncthreads();
  if (l15 == 0) {
#pragma unroll
    for (int mt2 = 0; mt2 < 3; ++mt2)
#pragma unroll
      for (int rg = 0; rg < 4; ++rg) {
        const int t = mt2 * 16 + quad * 4 + rg;
        if (t < 40) {
          atomicAdd(&lsCOS[t], pn[mt2 * 4 + rg]);
          atomicAdd(&lsWN[t], pw[mt2 * 4 + rg]);
        }
      }
  }
  __syncthreads();
  if (tid < 40) {
    const float w2 = sqrtf(lsWN[tid]);
    lsRED[tid] = lsCOS[tid] / fmaxf(cnorm[c * 40 + tid] * w2, 1e-8f);
  }
  __syncthreads();
  if (tid == 0) {
    float s = 0.f;
    for (int t = 0; t < 40; ++t) s += lsRED[t];
    s *= (1.f / 40.f);
    if (ITER == 1) sim1[pair] = s;
    else score[i * 32 + c] = s + sim1[pair];
  }
}

// ---------------------------------------------------------------------------
extern "C" void kernel_launch(void* const* d_in, const int* in_sizes, int n_in,
                              void* d_out, int out_size, void* d_ws, size_t ws_size,
                              hipStream_t stream) {
  const float* img = (const float*)d_in[0];   // [32][36][1024] fp32
  const float* cap = (const float*)d_in[1];   // [32][40][1024] fp32
  const float* Wl  = (const float*)d_in[2];   // [2048][1024] fp32
  const float* bl  = (const float*)d_in[3];   // [1024] fp32
  const float* Wg  = (const float*)d_in[4];
  const float* bg  = (const float*)d_in[5];
  float* out = (float*)d_out;                 // [32][32] fp32

  char* ws = (char*)d_ws;                 // total 186,393,856 B
  float* cnrm = (float*)ws;               ws += 5120;
  float* sim1 = (float*)ws;               ws += 4096;
  u16*   WTl  = (u16*)ws;                 ws += (size_t)1024 * 2048 * 2;   // 4.2 MB
  u16*   WTg  = (u16*)ws;                 ws += (size_t)1024 * 2048 * 2;   // 4.2 MB
  u16*   preL = (u16*)ws;                 ws += (size_t)1280 * 1024 * 2;   // 2.6 MB
  u16*   preG = (u16*)ws;                 ws += (size_t)1280 * 1024 * 2;   // 2.6 MB
  u16*   imgb = (u16*)ws;                 ws += (size_t)1152 * 1024 * 2;   // 2.4 MB
  u16*   ctxT = (u16*)ws;                 ws += (size_t)32 * 1024 * 40 * 2 + 256;
  u16*   wc1  = (u16*)ws;                 ws += (size_t)40960 * 1024 * 2;  // 83.9 MB
  u16*   q2   = (u16*)ws;                 ws += (size_t)40960 * 1024 * 2;  // 83.9 MB
  u16*   capb = q2;  // alias: capb dead before gemm_dual1 writes q2

  cvt_k<<<1152, 256, 0, stream>>>(img, imgb);
  cvt_k<<<1280, 256, 0, stream>>>(cap, capb);
  ctxt_k<<<128, 256, 0, stream>>>(img, ctxT);
  transpose_k<<<dim3(64, 32, 2), dim3(32, 8), 0, stream>>>(Wl, Wg, WTl, WTg);
  capnorm_k<<<320, 256, 0, stream>>>(cap, cnrm);
  gemm_pre<<<80, 256, 0, stream>>>(capb, WTl, WTg, preL, preG);
  attn_k<1><<<1024, 256, 0, stream>>>(imgb, capb, q2, ctxT, cap, wc1, cnrm, sim1, out);
  gemm_dual1<<<2560, 256, 0, stream>>>(wc1, WTl, WTg, preL, preG, cap, bl, bg, q2);
  attn_k<2><<<1024, 256, 0, stream>>>(imgb, capb, q2, ctxT, cap, wc1, cnrm, sim1, out);
}

// Round 10
// 483.778 us; speedup vs baseline: 1.5476x; 1.0348x over previous
//
#include <hip/hip_runtime.h>
#include <stdint.h>

// C=32 captions, I=32 images, T=40 words, R=36 regions, D=1024.
// Inputs fp32; output score [32,32] fp32.
// R10: gemm_dual1 (171.8 GF, at m97 plateau) eliminated via algebra:
//   wc1@W_bot = P·(ctx@W_bot)  (P = attn weights per (c,i))
// -> gemm_w<1>: img@W_bot (1152 rows, fp32 cw) + cwt_k transpose to [i][d][40],
// -> attn_k<1> fuses P·cwT + gating epilogue, writes q2 directly (wc1 gone).

typedef unsigned short u16;
typedef __attribute__((ext_vector_type(8))) short bf16x8;
typedef __attribute__((ext_vector_type(4))) float f32x4;

#define MFMA_BF16(a, b, c) __builtin_amdgcn_mfma_f32_16x16x32_bf16((a), (b), (c), 0, 0, 0)

__device__ __forceinline__ float bf2f(u16 u) {
  union { unsigned v; float f; } x; x.v = ((unsigned)u) << 16; return x.f;
}
__device__ __forceinline__ u16 f2bf(float f) {  // round-to-nearest-even
  union { float f; unsigned v; } x; x.f = f;
  return (u16)((x.v + 0x7fffu + ((x.v >> 16) & 1u)) >> 16);
}
// async 16B global->LDS (DMA; LDS dest = wave-uniform base + lane*16)
__device__ __forceinline__ void gl2lds16(const u16* g, u16* l) {
  __builtin_amdgcn_global_load_lds((const __attribute__((address_space(1))) void*)g,
                                   (__attribute__((address_space(3))) void*)l, 16, 0, 0);
}

// ---------------------------------------------------------------------------
__global__ void cvt_k(const float* __restrict__ src, u16* __restrict__ dst) {
  const int idx = (blockIdx.x * 256 + threadIdx.x) * 4;
  const float4 v = *(const float4*)(src + idx);
  u16 o[4] = {f2bf(v.x), f2bf(v.y), f2bf(v.z), f2bf(v.w)};
  *(uint2*)(dst + idx) = *(const uint2*)o;
}

// ---------------------------------------------------------------------------
// Build ctxT[i][d][40] bf16 from img fp32 [i][r][d]; r pad 36..39 = 0.
__global__ void ctxt_k(const float* __restrict__ img, u16* __restrict__ ctxT) {
  const int g = blockIdx.x * 256 + threadIdx.x;  // 32768 = 32 i * 1024 d
  const int i = g >> 10, d = g & 1023;
  u16 row[40];
#pragma unroll
  for (int r = 0; r < 36; ++r) row[r] = f2bf(img[((size_t)(i * 36 + r) << 10) + d]);
#pragma unroll
  for (int r = 36; r < 40; ++r) row[r] = 0;
  u16* dst = ctxT + (size_t)g * 40;
#pragma unroll
  for (int j = 0; j < 5; ++j) *(uint4*)(dst + j * 8) = *(const uint4*)(row + j * 8);
}

// Same but source is cw fp32 [i*36+r][1024] (ctx@W output).
__global__ void cwt_k(const float* __restrict__ cw, u16* __restrict__ cwT) {
  const int g = blockIdx.x * 256 + threadIdx.x;  // i*1024+d
  const int i = g >> 10, d = g & 1023;
  u16 row[40];
#pragma unroll
  for (int r = 0; r < 36; ++r) row[r] = f2bf(cw[((size_t)(i * 36 + r) << 10) + d]);
#pragma unroll
  for (int r = 36; r < 40; ++r) row[r] = 0;
  u16* dst = cwT + (size_t)g * 40;
#pragma unroll
  for (int j = 0; j < 5; ++j) *(uint4*)(dst + j * 8) = *(const uint4*)(row + j * 8);
}

// ---------------------------------------------------------------------------
__global__ void capnorm_k(const float* __restrict__ cap, float* __restrict__ cnorm) {
  const int wv = threadIdx.x >> 6, lane = threadIdx.x & 63;
  const int row = blockIdx.x * 4 + wv;  // < 1280
  const float* p = cap + ((size_t)row << 10) + lane * 16;
  float s = 0.f;
#pragma unroll
  for (int e = 0; e < 16; ++e) { float v = p[e]; s += v * v; }
#pragma unroll
  for (int off = 32; off > 0; off >>= 1) s += __shfl_down(s, off, 64);
  if (lane == 0) cnorm[row] = sqrtf(s);
}

// ---------------------------------------------------------------------------
__global__ void transpose_k(const float* __restrict__ Wl, const float* __restrict__ Wg,
                            u16* __restrict__ WTl, u16* __restrict__ WTg) {
  __shared__ u16 tile[32][33];
  const float* src = blockIdx.z ? Wg : Wl;
  u16* dst = blockIdx.z ? WTg : WTl;
  const int k0 = blockIdx.x * 32, n0 = blockIdx.y * 32;
  const int tx = threadIdx.x, ty = threadIdx.y;
#pragma unroll
  for (int j = 0; j < 4; ++j)
    tile[ty + 8 * j][tx] = f2bf(src[(size_t)(k0 + ty + 8 * j) * 1024 + n0 + tx]);
  __syncthreads();
#pragma unroll
  for (int j = 0; j < 4; ++j)
    dst[(size_t)(n0 + ty + 8 * j) * 2048 + k0 + tx] = tile[tx][ty + 8 * j];
}

// ---------------------------------------------------------------------------
// Dual-B GEMM: out{L,G}[m,n] = sum_k A[m,k]*W{l,g}[kofs+k][n], K=1024.
// IMGW=0: A=capb (M=1280, kofs=0, bf16 out). IMGW=1: A=imgb (M=1152, kofs=1024,
// fp32 out). 128x128 tile, BK=32, async staging.
template <int IMGW>
__global__ __launch_bounds__(256, 2) void gemm_w(
    const u16* __restrict__ A, const u16* __restrict__ WTl, const u16* __restrict__ WTg,
    void* __restrict__ outL_, void* __restrict__ outG_) {
  __shared__ __align__(16) u16 lsA[128 * 32];
  __shared__ __align__(16) u16 lsBl[128 * 32];
  __shared__ __align__(16) u16 lsBg[128 * 32];
  const int tid = threadIdx.x;
  const int bm = blockIdx.x >> 3, bn = blockIdx.x & 7;
  const int wv = tid >> 6, lane = tid & 63;
  const int quad = lane >> 4, l15 = lane & 15;
  const int wm = (wv & 1) << 6, wn = (wv >> 1) << 6;
  const int kofs = IMGW ? 1024 : 0;

  f32x4 accL[4][4], accG[4][4];
#pragma unroll
  for (int a = 0; a < 4; ++a)
#pragma unroll
    for (int b = 0; b < 4; ++b) {
      accL[a][b] = (f32x4){0.f, 0.f, 0.f, 0.f};
      accG[a][b] = (f32x4){0.f, 0.f, 0.f, 0.f};
    }

  const size_t arow0 = (size_t)bm * 128 * 1024;
  for (int kt = 0; kt < 32; ++kt) {
    if (kt) __syncthreads();
#pragma unroll
    for (int s = 0; s < 2; ++s) {
      const int idx = s * 256 + tid;
      const int row = idx >> 2, c8 = idx & 3;
      gl2lds16(A + arow0 + (size_t)row * 1024 + kt * 32 + c8 * 8,
               lsA + (size_t)(s * 256 + wv * 64) * 8);
      const size_t bro = (size_t)(bn * 128 + row) * 2048 + kofs + kt * 32 + c8 * 8;
      gl2lds16(WTl + bro, lsBl + (size_t)(s * 256 + wv * 64) * 8);
      gl2lds16(WTg + bro, lsBg + (size_t)(s * 256 + wv * 64) * 8);
    }
    __syncthreads();
    bf16x8 af[4], bl8[4], bg8[4];
#pragma unroll
    for (int mt = 0; mt < 4; ++mt)
      af[mt] = *(const bf16x8*)(lsA + (wm + mt * 16 + l15) * 32 + quad * 8);
#pragma unroll
    for (int nt = 0; nt < 4; ++nt) {
      bl8[nt] = *(const bf16x8*)(lsBl + (wn + nt * 16 + l15) * 32 + quad * 8);
      bg8[nt] = *(const bf16x8*)(lsBg + (wn + nt * 16 + l15) * 32 + quad * 8);
    }
#pragma unroll
    for (int mt = 0; mt < 4; ++mt)
#pragma unroll
      for (int nt = 0; nt < 4; ++nt) {
        accL[mt][nt] = MFMA_BF16(af[mt], bl8[nt], accL[mt][nt]);
        accG[mt][nt] = MFMA_BF16(af[mt], bg8[nt], accG[mt][nt]);
      }
  }
#pragma unroll
  for (int mt = 0; mt < 4; ++mt)
#pragma unroll
    for (int nt = 0; nt < 4; ++nt)
#pragma unroll
      for (int r = 0; r < 4; ++r) {
        const int m = bm * 128 + wm + mt * 16 + quad * 4 + r;
        const int n = bn * 128 + wn + nt * 16 + l15;
        if (IMGW) {
          ((float*)outL_)[(size_t)m * 1024 + n] = accL[mt][nt][r];
          ((float*)outG_)[(size_t)m * 1024 + n] = accG[mt][nt][r];
        } else {
          ((u16*)outL_)[(size_t)m * 1024 + n] = f2bf(accL[mt][nt][r]);
          ((u16*)outG_)[(size_t)m * 1024 + n] = f2bf(accG[mt][nt][r]);
        }
      }
}

// ---------------------------------------------------------------------------
// Barrier-free fused attention. ITER 1: query=cap; computes sim1 AND
// q2 = cap*g + tanh(P·cwT + pre + b)*(1-g) (gated memory fused via algebra).
// ITER 2: query=q2, writes score = sim1 + sim2.
template <int ITER>
__global__ __launch_bounds__(256, 2) void attn_k(
    const u16* __restrict__ imgb, const u16* __restrict__ capb,
    const u16* __restrict__ q2v, const u16* __restrict__ ctxT,
    const u16* __restrict__ cwTL, const u16* __restrict__ cwTG,
    const u16* __restrict__ preL, const u16* __restrict__ preG,
    const float* __restrict__ capf, const float* __restrict__ bL,
    const float* __restrict__ bG, u16* __restrict__ q2o,
    const float* __restrict__ cnorm, float* __restrict__ sim1,
    float* __restrict__ score) {
  __shared__ __align__(16) u16 lsAT[4][48 * 72];
  __shared__ float lsCOS[48], lsWN[48], lsRED[48];

  const int tid = threadIdx.x;
  const int c = blockIdx.x >> 5, i = blockIdx.x & 31;
  const int pair = c * 32 + i;
  const int wv = tid >> 6, lane = tid & 63;
  const int quad = lane >> 4, l15 = lane & 15;

  {
    unsigned* z = (unsigned*)lsAT[wv];
    for (int k = lane; k < 1728; k += 64) z[k] = 0u;
    if (tid < 48) { lsCOS[tid] = 0.f; lsWN[tid] = 0.f; }
  }

  const u16* arow[3]; bool avalid[3];
  const u16* brow[3]; bool bvalid[3];
#pragma unroll
  for (int mt = 0; mt < 3; ++mt) {
    const int r = mt * 16 + l15;
    avalid[mt] = r < 36;
    arow[mt] = imgb + ((size_t)(i * 36 + (r < 36 ? r : 35)) << 10);
  }
#pragma unroll
  for (int nt = 0; nt < 3; ++nt) {
    const int t = nt * 16 + l15;
    bvalid[nt] = t < 40;
    const int tc = t < 40 ? t : 39;
    brow[nt] = (ITER == 1) ? (capb + ((size_t)(c * 40 + tc) << 10))
                           : (q2v + ((size_t)(pair * 40 + tc) << 10));
  }
  const bf16x8 zero8 = {0, 0, 0, 0, 0, 0, 0, 0};

  f32x4 accS[3][3];
#pragma unroll
  for (int a = 0; a < 3; ++a)
#pragma unroll
    for (int b = 0; b < 3; ++b) accS[a][b] = (f32x4){0.f, 0.f, 0.f, 0.f};

  for (int kk = 0; kk < 32; ++kk) {
    const int ko = kk * 32 + quad * 8;
    bf16x8 af[3], bq[3];
#pragma unroll
    for (int mt = 0; mt < 3; ++mt)
      af[mt] = avalid[mt] ? *(const bf16x8*)(arow[mt] + ko) : zero8;
#pragma unroll
    for (int nt = 0; nt < 3; ++nt)
      bq[nt] = bvalid[nt] ? *(const bf16x8*)(brow[nt] + ko) : zero8;
#pragma unroll
    for (int mt = 0; mt < 3; ++mt)
#pragma unroll
      for (int nt = 0; nt < 3; ++nt)
        accS[mt][nt] = MFMA_BF16(af[mt], bq[nt], accS[mt][nt]);
  }

  float rn[3][4];
#pragma unroll
  for (int mt = 0; mt < 3; ++mt)
#pragma unroll
    for (int rg = 0; rg < 4; ++rg) {
      float s2 = 0.f;
#pragma unroll
      for (int nt = 0; nt < 3; ++nt) {
        float v = accS[mt][nt][rg]; v = v > 0.f ? v : 0.1f * v; s2 += v * v;
      }
      s2 += __shfl_xor(s2, 1, 64); s2 += __shfl_xor(s2, 2, 64);
      s2 += __shfl_xor(s2, 4, 64); s2 += __shfl_xor(s2, 8, 64);
      rn[mt][rg] = sqrtf(s2) + 1e-8f;
    }
  float mx[3] = {-3.0e38f, -3.0e38f, -3.0e38f};
#pragma unroll
  for (int mt = 0; mt < 3; ++mt)
#pragma unroll
    for (int nt = 0; nt < 3; ++nt)
#pragma unroll
      for (int rg = 0; rg < 4; ++rg) {
        const int r = mt * 16 + quad * 4 + rg;
        float v = accS[mt][nt][rg]; v = v > 0.f ? v : 0.1f * v;
        float zz = 9.f * v / rn[mt][rg];
        zz = (r < 36) ? zz : -3.0e38f;
        accS[mt][nt][rg] = zz;
        mx[nt] = fmaxf(mx[nt], zz);
      }
#pragma unroll
  for (int nt = 0; nt < 3; ++nt) {
    mx[nt] = fmaxf(mx[nt], __shfl_xor(mx[nt], 16, 64));
    mx[nt] = fmaxf(mx[nt], __shfl_xor(mx[nt], 32, 64));
  }
  float ss[3] = {0.f, 0.f, 0.f};
#pragma unroll
  for (int mt = 0; mt < 3; ++mt)
#pragma unroll
    for (int nt = 0; nt < 3; ++nt)
#pragma unroll
      for (int rg = 0; rg < 4; ++rg) {
        const float e = __expf(accS[mt][nt][rg] - mx[nt]);
        accS[mt][nt][rg] = e; ss[nt] += e;
      }
#pragma unroll
  for (int nt = 0; nt < 3; ++nt) {
    ss[nt] += __shfl_xor(ss[nt], 16, 64);
    ss[nt] += __shfl_xor(ss[nt], 32, 64);
    ss[nt] = 1.f / ss[nt];
  }
#pragma unroll
  for (int nt = 0; nt < 3; ++nt) {
    const int t = nt * 16 + l15;
    if (t < 40) {
#pragma unroll
      for (int mt = 0; mt < 3; ++mt)
#pragma unroll
        for (int rg = 0; rg < 4; ++rg)
          lsAT[wv][t * 72 + mt * 16 + quad * 4 + rg] = f2bf(accS[mt][nt][rg] * ss[nt]);
    }
  }

  // ---- phase 2: wc = P@ctx (cosine) and, for ITER 1, q2 = gate(P@cwT).
  bf16x8 afA[3][2];
#pragma unroll
  for (int mt2 = 0; mt2 < 3; ++mt2)
#pragma unroll
    for (int ks = 0; ks < 2; ++ks)
      afA[mt2][ks] = *(const bf16x8*)(lsAT[wv] + (mt2 * 16 + l15) * 72 + ks * 32 + quad * 8);

  float pn[12], pw[12];
#pragma unroll
  for (int k = 0; k < 12; ++k) { pn[k] = 0.f; pw[k] = 0.f; }

  const int dbase = wv * 256;
  for (int nt2 = 0; nt2 < 16; ++nt2) {
    const int d = dbase + nt2 * 16 + l15;
    const u16* bp = ctxT + ((size_t)(i << 10) + d) * 40;
    const bf16x8 b0 = *(const bf16x8*)(bp + quad * 8);
    const bf16x8 b1 = *(const bf16x8*)(bp + 32 + quad * 8);  // overrun x0
    f32x4 acc[3];
#pragma unroll
    for (int mt2 = 0; mt2 < 3; ++mt2) {
      acc[mt2] = (f32x4){0.f, 0.f, 0.f, 0.f};
      acc[mt2] = MFMA_BF16(afA[mt2][0], b0, acc[mt2]);
      acc[mt2] = MFMA_BF16(afA[mt2][1], b1, acc[mt2]);
    }
#pragma unroll
    for (int mt2 = 0; mt2 < 3; ++mt2)
#pragma unroll
      for (int rg = 0; rg < 4; ++rg) {
        const int t = mt2 * 16 + quad * 4 + rg;
        if (t < 40) {
          const float w = acc[mt2][rg];
          const float cv = capf[((size_t)(c * 40 + t) << 10) + d];
          pn[mt2 * 4 + rg] += cv * w;
          pw[mt2 * 4 + rg] += w * w;
        }
      }
    if (ITER == 1) {  // gated memory: q2 = cap*g + tanh(P·cwL + preL + bL)*(1-g)
      const u16* bpl = cwTL + ((size_t)(i << 10) + d) * 40;
      const u16* bpg = cwTG + ((size_t)(i << 10) + d) * 40;
      const bf16x8 cl0 = *(const bf16x8*)(bpl + quad * 8);
      const bf16x8 cl1 = *(const bf16x8*)(bpl + 32 + quad * 8);
      const bf16x8 cg0 = *(const bf16x8*)(bpg + quad * 8);
      const bf16x8 cg1 = *(const bf16x8*)(bpg + 32 + quad * 8);
      f32x4 aqL[3], aqG[3];
#pragma unroll
      for (int mt2 = 0; mt2 < 3; ++mt2) {
        aqL[mt2] = (f32x4){0.f, 0.f, 0.f, 0.f};
        aqL[mt2] = MFMA_BF16(afA[mt2][0], cl0, aqL[mt2]);
        aqL[mt2] = MFMA_BF16(afA[mt2][1], cl1, aqL[mt2]);
        aqG[mt2] = (f32x4){0.f, 0.f, 0.f, 0.f};
        aqG[mt2] = MFMA_BF16(afA[mt2][0], cg0, aqG[mt2]);
        aqG[mt2] = MFMA_BF16(afA[mt2][1], cg1, aqG[mt2]);
      }
      const float bLv = bL[d], bGv = bG[d];
#pragma unroll
      for (int mt2 = 0; mt2 < 3; ++mt2)
#pragma unroll
        for (int rg = 0; rg < 4; ++rg) {
          const int t = mt2 * 16 + quad * 4 + rg;
          if (t < 40) {
            const size_t ctd = ((size_t)(c * 40 + t) << 10) + d;
            const float aL = aqL[mt2][rg] + bf2f(preL[ctd]) + bLv;
            const float aG = aqG[mt2][rg] + bf2f(preG[ctd]) + bGv;
            const float g = 1.f / (1.f + __expf(-aG));
            const float u = 2.f / (1.f + __expf(-2.f * aL)) - 1.f;  // tanh
            q2o[((size_t)(pair * 40 + t) << 10) + d] =
                f2bf(capf[ctd] * g + u * (1.f - g));
          }
        }
    }
  }
#pragma unroll
  for (int k = 0; k < 12; ++k) {
#pragma unroll
    for (int off = 1; off <= 8; off <<= 1) {
      pn[k] += __shfl_xor(pn[k], off, 64);
      pw[k] += __shfl_xor(pw[k], off, 64);
    }
  }
  __syncthreads();
  if (l15 == 0) {
#pragma unroll
    for (int mt2 = 0; mt2 < 3; ++mt2)
#pragma unroll
      for (int rg = 0; rg < 4; ++rg) {
        const int t = mt2 * 16 + quad * 4 + rg;
        if (t < 40) {
          atomicAdd(&lsCOS[t], pn[mt2 * 4 + rg]);
          atomicAdd(&lsWN[t], pw[mt2 * 4 + rg]);
        }
      }
  }
  __syncthreads();
  if (tid < 40) {
    const float w2 = sqrtf(lsWN[tid]);
    lsRED[tid] = lsCOS[tid] / fmaxf(cnorm[c * 40 + tid] * w2, 1e-8f);
  }
  __syncthreads();
  if (tid == 0) {
    float s = 0.f;
    for (int t = 0; t < 40; ++t) s += lsRED[t];
    s *= (1.f / 40.f);
    if (ITER == 1) sim1[pair] = s;
    else score[i * 32 + c] = s + sim1[pair];
  }
}

// ---------------------------------------------------------------------------
extern "C" void kernel_launch(void* const* d_in, const int* in_sizes, int n_in,
                              void* d_out, int out_size, void* d_ws, size_t ws_size,
                              hipStream_t stream) {
  const float* img = (const float*)d_in[0];   // [32][36][1024] fp32
  const float* cap = (const float*)d_in[1];   // [32][40][1024] fp32
  const float* Wl  = (const float*)d_in[2];   // [2048][1024] fp32
  const float* bl  = (const float*)d_in[3];   // [1024] fp32
  const float* Wg  = (const float*)d_in[4];
  const float* bg  = (const float*)d_in[5];
  float* out = (float*)d_out;                 // [32][32] fp32

  char* ws = (char*)d_ws;                 // total ~120 MB
  float* cnrm = (float*)ws;               ws += 5120;
  float* sim1 = (float*)ws;               ws += 4096;
  u16*   WTl  = (u16*)ws;                 ws += (size_t)1024 * 2048 * 2;   // 4.2 MB
  u16*   WTg  = (u16*)ws;                 ws += (size_t)1024 * 2048 * 2;   // 4.2 MB
  u16*   preL = (u16*)ws;                 ws += (size_t)1280 * 1024 * 2;   // 2.6 MB
  u16*   preG = (u16*)ws;                 ws += (size_t)1280 * 1024 * 2;   // 2.6 MB
  u16*   imgb = (u16*)ws;                 ws += (size_t)1152 * 1024 * 2;   // 2.4 MB
  u16*   capb = (u16*)ws;                 ws += (size_t)1280 * 1024 * 2;   // 2.6 MB
  u16*   ctxT = (u16*)ws;                 ws += (size_t)32 * 1024 * 40 * 2 + 256;
  u16*   cwTL = (u16*)ws;                 ws += (size_t)32 * 1024 * 40 * 2 + 256;
  u16*   cwTG = (u16*)ws;                 ws += (size_t)32 * 1024 * 40 * 2 + 256;
  float* cwL  = (float*)ws;               ws += (size_t)1152 * 1024 * 4;   // 4.7 MB
  float* cwG  = (float*)ws;               ws += (size_t)1152 * 1024 * 4;   // 4.7 MB
  u16*   q2   = (u16*)ws;                 ws += (size_t)40960 * 1024 * 2;  // 83.9 MB

  cvt_k<<<1152, 256, 0, stream>>>(img, imgb);
  cvt_k<<<1280, 256, 0, stream>>>(cap, capb);
  ctxt_k<<<128, 256, 0, stream>>>(img, ctxT);
  transpose_k<<<dim3(64, 32, 2), dim3(32, 8), 0, stream>>>(Wl, Wg, WTl, WTg);
  capnorm_k<<<320, 256, 0, stream>>>(cap, cnrm);
  gemm_w<0><<<80, 256, 0, stream>>>(capb, WTl, WTg, preL, preG);   // cap@W_top
  gemm_w<1><<<72, 256, 0, stream>>>(imgb, WTl, WTg, cwL, cwG);     // img@W_bot
  cwt_k<<<128, 256, 0, stream>>>(cwL, cwTL);
  cwt_k<<<128, 256, 0, stream>>>(cwG, cwTG);
  attn_k<1><<<1024, 256, 0, stream>>>(imgb, capb, q2, ctxT, cwTL, cwTG, preL, preG,
                                      cap, bl, bg, q2, cnrm, sim1, out);
  attn_k<2><<<1024, 256, 0, stream>>>(imgb, capb, q2, ctxT, cwTL, cwTG, preL, preG,
                                      cap, bl, bg, q2, cnrm, sim1, out);
}

// Round 11
// 465.438 us; speedup vs baseline: 1.6086x; 1.0394x over previous
//
#include <hip/hip_runtime.h>
#include <stdint.h>

// C=32 captions, I=32 images, T=40 words, R=36 regions, D=1024.
// Inputs fp32; output score [32,32] fp32.
// R11: attn phase-1 de-redundified: K=1024 split across the 4 waves
// (each kk in [wv*8,wv*8+8)), partial S reduced via LDS atomicAdd
// (lsS stride 49), re-read in C-layout, then R7 shuffle-softmax unchanged.

typedef unsigned short u16;
typedef __attribute__((ext_vector_type(8))) short bf16x8;
typedef __attribute__((ext_vector_type(4))) float f32x4;

#define MFMA_BF16(a, b, c) __builtin_amdgcn_mfma_f32_16x16x32_bf16((a), (b), (c), 0, 0, 0)

__device__ __forceinline__ float bf2f(u16 u) {
  union { unsigned v; float f; } x; x.v = ((unsigned)u) << 16; return x.f;
}
__device__ __forceinline__ u16 f2bf(float f) {  // round-to-nearest-even
  union { float f; unsigned v; } x; x.f = f;
  return (u16)((x.v + 0x7fffu + ((x.v >> 16) & 1u)) >> 16);
}
// async 16B global->LDS (DMA; LDS dest = wave-uniform base + lane*16)
__device__ __forceinline__ void gl2lds16(const u16* g, u16* l) {
  __builtin_amdgcn_global_load_lds((const __attribute__((address_space(1))) void*)g,
                                   (__attribute__((address_space(3))) void*)l, 16, 0, 0);
}

// ---------------------------------------------------------------------------
__global__ void cvt_k(const float* __restrict__ src, u16* __restrict__ dst) {
  const int idx = (blockIdx.x * 256 + threadIdx.x) * 4;
  const float4 v = *(const float4*)(src + idx);
  u16 o[4] = {f2bf(v.x), f2bf(v.y), f2bf(v.z), f2bf(v.w)};
  *(uint2*)(dst + idx) = *(const uint2*)o;
}

// ---------------------------------------------------------------------------
// Build ctxT[i][d][40] bf16 from img fp32 [i][r][d]; r pad 36..39 = 0.
__global__ void ctxt_k(const float* __restrict__ img, u16* __restrict__ ctxT) {
  const int g = blockIdx.x * 256 + threadIdx.x;  // 32768 = 32 i * 1024 d
  const int i = g >> 10, d = g & 1023;
  u16 row[40];
#pragma unroll
  for (int r = 0; r < 36; ++r) row[r] = f2bf(img[((size_t)(i * 36 + r) << 10) + d]);
#pragma unroll
  for (int r = 36; r < 40; ++r) row[r] = 0;
  u16* dst = ctxT + (size_t)g * 40;
#pragma unroll
  for (int j = 0; j < 5; ++j) *(uint4*)(dst + j * 8) = *(const uint4*)(row + j * 8);
}

// Same but source is cw fp32 [i*36+r][1024] (ctx@W output).
__global__ void cwt_k(const float* __restrict__ cw, u16* __restrict__ cwT) {
  const int g = blockIdx.x * 256 + threadIdx.x;  // i*1024+d
  const int i = g >> 10, d = g & 1023;
  u16 row[40];
#pragma unroll
  for (int r = 0; r < 36; ++r) row[r] = f2bf(cw[((size_t)(i * 36 + r) << 10) + d]);
#pragma unroll
  for (int r = 36; r < 40; ++r) row[r] = 0;
  u16* dst = cwT + (size_t)g * 40;
#pragma unroll
  for (int j = 0; j < 5; ++j) *(uint4*)(dst + j * 8) = *(const uint4*)(row + j * 8);
}

// ---------------------------------------------------------------------------
__global__ void capnorm_k(const float* __restrict__ cap, float* __restrict__ cnorm) {
  const int wv = threadIdx.x >> 6, lane = threadIdx.x & 63;
  const int row = blockIdx.x * 4 + wv;  // < 1280
  const float* p = cap + ((size_t)row << 10) + lane * 16;
  float s = 0.f;
#pragma unroll
  for (int e = 0; e < 16; ++e) { float v = p[e]; s += v * v; }
#pragma unroll
  for (int off = 32; off > 0; off >>= 1) s += __shfl_down(s, off, 64);
  if (lane == 0) cnorm[row] = sqrtf(s);
}

// ---------------------------------------------------------------------------
__global__ void transpose_k(const float* __restrict__ Wl, const float* __restrict__ Wg,
                            u16* __restrict__ WTl, u16* __restrict__ WTg) {
  __shared__ u16 tile[32][33];
  const float* src = blockIdx.z ? Wg : Wl;
  u16* dst = blockIdx.z ? WTg : WTl;
  const int k0 = blockIdx.x * 32, n0 = blockIdx.y * 32;
  const int tx = threadIdx.x, ty = threadIdx.y;
#pragma unroll
  for (int j = 0; j < 4; ++j)
    tile[ty + 8 * j][tx] = f2bf(src[(size_t)(k0 + ty + 8 * j) * 1024 + n0 + tx]);
  __syncthreads();
#pragma unroll
  for (int j = 0; j < 4; ++j)
    dst[(size_t)(n0 + ty + 8 * j) * 2048 + k0 + tx] = tile[tx][ty + 8 * j];
}

// ---------------------------------------------------------------------------
// Dual-B GEMM: out{L,G}[m,n] = sum_k A[m,k]*W{l,g}[kofs+k][n], K=1024.
// IMGW=0: A=capb (M=1280, kofs=0, bf16 out). IMGW=1: A=imgb (M=1152, kofs=1024,
// fp32 out). 128x128 tile, BK=32, async staging.
template <int IMGW>
__global__ __launch_bounds__(256, 2) void gemm_w(
    const u16* __restrict__ A, const u16* __restrict__ WTl, const u16* __restrict__ WTg,
    void* __restrict__ outL_, void* __restrict__ outG_) {
  __shared__ __align__(16) u16 lsA[128 * 32];
  __shared__ __align__(16) u16 lsBl[128 * 32];
  __shared__ __align__(16) u16 lsBg[128 * 32];
  const int tid = threadIdx.x;
  const int bm = blockIdx.x >> 3, bn = blockIdx.x & 7;
  const int wv = tid >> 6, lane = tid & 63;
  const int quad = lane >> 4, l15 = lane & 15;
  const int wm = (wv & 1) << 6, wn = (wv >> 1) << 6;
  const int kofs = IMGW ? 1024 : 0;

  f32x4 accL[4][4], accG[4][4];
#pragma unroll
  for (int a = 0; a < 4; ++a)
#pragma unroll
    for (int b = 0; b < 4; ++b) {
      accL[a][b] = (f32x4){0.f, 0.f, 0.f, 0.f};
      accG[a][b] = (f32x4){0.f, 0.f, 0.f, 0.f};
    }

  const size_t arow0 = (size_t)bm * 128 * 1024;
  for (int kt = 0; kt < 32; ++kt) {
    if (kt) __syncthreads();
#pragma unroll
    for (int s = 0; s < 2; ++s) {
      const int idx = s * 256 + tid;
      const int row = idx >> 2, c8 = idx & 3;
      gl2lds16(A + arow0 + (size_t)row * 1024 + kt * 32 + c8 * 8,
               lsA + (size_t)(s * 256 + wv * 64) * 8);
      const size_t bro = (size_t)(bn * 128 + row) * 2048 + kofs + kt * 32 + c8 * 8;
      gl2lds16(WTl + bro, lsBl + (size_t)(s * 256 + wv * 64) * 8);
      gl2lds16(WTg + bro, lsBg + (size_t)(s * 256 + wv * 64) * 8);
    }
    __syncthreads();
    bf16x8 af[4], bl8[4], bg8[4];
#pragma unroll
    for (int mt = 0; mt < 4; ++mt)
      af[mt] = *(const bf16x8*)(lsA + (wm + mt * 16 + l15) * 32 + quad * 8);
#pragma unroll
    for (int nt = 0; nt < 4; ++nt) {
      bl8[nt] = *(const bf16x8*)(lsBl + (wn + nt * 16 + l15) * 32 + quad * 8);
      bg8[nt] = *(const bf16x8*)(lsBg + (wn + nt * 16 + l15) * 32 + quad * 8);
    }
#pragma unroll
    for (int mt = 0; mt < 4; ++mt)
#pragma unroll
      for (int nt = 0; nt < 4; ++nt) {
        accL[mt][nt] = MFMA_BF16(af[mt], bl8[nt], accL[mt][nt]);
        accG[mt][nt] = MFMA_BF16(af[mt], bg8[nt], accG[mt][nt]);
      }
  }
#pragma unroll
  for (int mt = 0; mt < 4; ++mt)
#pragma unroll
    for (int nt = 0; nt < 4; ++nt)
#pragma unroll
      for (int r = 0; r < 4; ++r) {
        const int m = bm * 128 + wm + mt * 16 + quad * 4 + r;
        const int n = bn * 128 + wn + nt * 16 + l15;
        if (IMGW) {
          ((float*)outL_)[(size_t)m * 1024 + n] = accL[mt][nt][r];
          ((float*)outG_)[(size_t)m * 1024 + n] = accG[mt][nt][r];
        } else {
          ((u16*)outL_)[(size_t)m * 1024 + n] = f2bf(accL[mt][nt][r]);
          ((u16*)outG_)[(size_t)m * 1024 + n] = f2bf(accG[mt][nt][r]);
        }
      }
}

// ---------------------------------------------------------------------------
// Fused attention. ITER 1: query=cap; sim1 + q2 = gate(P·cwT + pre + b).
// ITER 2: query=q2, score = sim1 + sim2.
// R11: phase 1 split across waves (K/4 each) + LDS reduction of S.
template <int ITER>
__global__ __launch_bounds__(256, 2) void attn_k(
    const u16* __restrict__ imgb, const u16* __restrict__ capb,
    const u16* __restrict__ q2v, const u16* __restrict__ ctxT,
    const u16* __restrict__ cwTL, const u16* __restrict__ cwTG,
    const u16* __restrict__ preL, const u16* __restrict__ preG,
    const float* __restrict__ capf, const float* __restrict__ bL,
    const float* __restrict__ bG, u16* __restrict__ q2o,
    const float* __restrict__ cnorm, float* __restrict__ sim1,
    float* __restrict__ score) {
  __shared__ __align__(16) u16 lsAT[4][48 * 72];
  __shared__ float lsS[48 * 49];   // stride-49 pad: cross-quad bank stagger
  __shared__ float lsCOS[48], lsWN[48], lsRED[48];

  const int tid = threadIdx.x;
  const int c = blockIdx.x >> 5, i = blockIdx.x & 31;
  const int pair = c * 32 + i;
  const int wv = tid >> 6, lane = tid & 63;
  const int quad = lane >> 4, l15 = lane & 15;

  {
    unsigned* z = (unsigned*)lsAT[wv];
    for (int k = lane; k < 1728; k += 64) z[k] = 0u;
    for (int k = tid; k < 2352; k += 256) lsS[k] = 0.f;
    if (tid < 48) { lsCOS[tid] = 0.f; lsWN[tid] = 0.f; }
  }

  const u16* arow[3]; bool avalid[3];
  const u16* brow[3]; bool bvalid[3];
#pragma unroll
  for (int mt = 0; mt < 3; ++mt) {
    const int r = mt * 16 + l15;
    avalid[mt] = r < 36;
    arow[mt] = imgb + ((size_t)(i * 36 + (r < 36 ? r : 35)) << 10);
  }
#pragma unroll
  for (int nt = 0; nt < 3; ++nt) {
    const int t = nt * 16 + l15;
    bvalid[nt] = t < 40;
    const int tc = t < 40 ? t : 39;
    brow[nt] = (ITER == 1) ? (capb + ((size_t)(c * 40 + tc) << 10))
                           : (q2v + ((size_t)(pair * 40 + tc) << 10));
  }
  const bf16x8 zero8 = {0, 0, 0, 0, 0, 0, 0, 0};

  // ---- phase 1: partial S over this wave's K-range [wv*256, wv*256+256)
  f32x4 accS[3][3];
#pragma unroll
  for (int a = 0; a < 3; ++a)
#pragma unroll
    for (int b = 0; b < 3; ++b) accS[a][b] = (f32x4){0.f, 0.f, 0.f, 0.f};

  for (int kk = wv * 8; kk < wv * 8 + 8; ++kk) {
    const int ko = kk * 32 + quad * 8;
    bf16x8 af[3], bq[3];
#pragma unroll
    for (int mt = 0; mt < 3; ++mt)
      af[mt] = avalid[mt] ? *(const bf16x8*)(arow[mt] + ko) : zero8;
#pragma unroll
    for (int nt = 0; nt < 3; ++nt)
      bq[nt] = bvalid[nt] ? *(const bf16x8*)(brow[nt] + ko) : zero8;
#pragma unroll
    for (int mt = 0; mt < 3; ++mt)
#pragma unroll
      for (int nt = 0; nt < 3; ++nt)
        accS[mt][nt] = MFMA_BF16(af[mt], bq[nt], accS[mt][nt]);
  }
  // ---- cross-wave reduction of S (zeros visible after barrier)
  __syncthreads();
#pragma unroll
  for (int mt = 0; mt < 3; ++mt)
#pragma unroll
    for (int nt = 0; nt < 3; ++nt)
#pragma unroll
      for (int rg = 0; rg < 4; ++rg)
        atomicAdd(&lsS[(mt * 16 + quad * 4 + rg) * 49 + nt * 16 + l15],
                  accS[mt][nt][rg]);
  __syncthreads();
  float sS[3][3][4];
#pragma unroll
  for (int mt = 0; mt < 3; ++mt)
#pragma unroll
    for (int nt = 0; nt < 3; ++nt)
#pragma unroll
      for (int rg = 0; rg < 4; ++rg)
        sS[mt][nt][rg] = lsS[(mt * 16 + quad * 4 + rg) * 49 + nt * 16 + l15];

  // ---- in-register leaky + l2norm over t, softmax over r (full S per wave)
  float rn[3][4];
#pragma unroll
  for (int mt = 0; mt < 3; ++mt)
#pragma unroll
    for (int rg = 0; rg < 4; ++rg) {
      float s2 = 0.f;
#pragma unroll
      for (int nt = 0; nt < 3; ++nt) {
        float v = sS[mt][nt][rg]; v = v > 0.f ? v : 0.1f * v; s2 += v * v;
      }
      s2 += __shfl_xor(s2, 1, 64); s2 += __shfl_xor(s2, 2, 64);
      s2 += __shfl_xor(s2, 4, 64); s2 += __shfl_xor(s2, 8, 64);
      rn[mt][rg] = sqrtf(s2) + 1e-8f;
    }
  float mx[3] = {-3.0e38f, -3.0e38f, -3.0e38f};
#pragma unroll
  for (int mt = 0; mt < 3; ++mt)
#pragma unroll
    for (int nt = 0; nt < 3; ++nt)
#pragma unroll
      for (int rg = 0; rg < 4; ++rg) {
        const int r = mt * 16 + quad * 4 + rg;
        float v = sS[mt][nt][rg]; v = v > 0.f ? v : 0.1f * v;
        float zz = 9.f * v / rn[mt][rg];
        zz = (r < 36) ? zz : -3.0e38f;
        sS[mt][nt][rg] = zz;
        mx[nt] = fmaxf(mx[nt], zz);
      }
#pragma unroll
  for (int nt = 0; nt < 3; ++nt) {
    mx[nt] = fmaxf(mx[nt], __shfl_xor(mx[nt], 16, 64));
    mx[nt] = fmaxf(mx[nt], __shfl_xor(mx[nt], 32, 64));
  }
  float ss[3] = {0.f, 0.f, 0.f};
#pragma unroll
  for (int mt = 0; mt < 3; ++mt)
#pragma unroll
    for (int nt = 0; nt < 3; ++nt)
#pragma unroll
      for (int rg = 0; rg < 4; ++rg) {
        const float e = __expf(sS[mt][nt][rg] - mx[nt]);
        sS[mt][nt][rg] = e; ss[nt] += e;
      }
#pragma unroll
  for (int nt = 0; nt < 3; ++nt) {
    ss[nt] += __shfl_xor(ss[nt], 16, 64);
    ss[nt] += __shfl_xor(ss[nt], 32, 64);
    ss[nt] = 1.f / ss[nt];
  }
#pragma unroll
  for (int nt = 0; nt < 3; ++nt) {
    const int t = nt * 16 + l15;
    if (t < 40) {
#pragma unroll
      for (int mt = 0; mt < 3; ++mt)
#pragma unroll
        for (int rg = 0; rg < 4; ++rg)
          lsAT[wv][t * 72 + mt * 16 + quad * 4 + rg] = f2bf(sS[mt][nt][rg] * ss[nt]);
    }
  }

  // ---- phase 2: wc = P@ctx (cosine) and, for ITER 1, q2 = gate(P@cwT).
  bf16x8 afA[3][2];
#pragma unroll
  for (int mt2 = 0; mt2 < 3; ++mt2)
#pragma unroll
    for (int ks = 0; ks < 2; ++ks)
      afA[mt2][ks] = *(const bf16x8*)(lsAT[wv] + (mt2 * 16 + l15) * 72 + ks * 32 + quad * 8);

  float pn[12], pw[12];
#pragma unroll
  for (int k = 0; k < 12; ++k) { pn[k] = 0.f; pw[k] = 0.f; }

  const int dbase = wv * 256;
  for (int nt2 = 0; nt2 < 16; ++nt2) {
    const int d = dbase + nt2 * 16 + l15;
    const u16* bp = ctxT + ((size_t)(i << 10) + d) * 40;
    const bf16x8 b0 = *(const bf16x8*)(bp + quad * 8);
    const bf16x8 b1 = *(const bf16x8*)(bp + 32 + quad * 8);  // overrun x0
    f32x4 acc[3];
#pragma unroll
    for (int mt2 = 0; mt2 < 3; ++mt2) {
      acc[mt2] = (f32x4){0.f, 0.f, 0.f, 0.f};
      acc[mt2] = MFMA_BF16(afA[mt2][0], b0, acc[mt2]);
      acc[mt2] = MFMA_BF16(afA[mt2][1], b1, acc[mt2]);
    }
#pragma unroll
    for (int mt2 = 0; mt2 < 3; ++mt2)
#pragma unroll
      for (int rg = 0; rg < 4; ++rg) {
        const int t = mt2 * 16 + quad * 4 + rg;
        if (t < 40) {
          const float w = acc[mt2][rg];
          const float cv = capf[((size_t)(c * 40 + t) << 10) + d];
          pn[mt2 * 4 + rg] += cv * w;
          pw[mt2 * 4 + rg] += w * w;
        }
      }
    if (ITER == 1) {  // gated memory: q2 = cap*g + tanh(P·cwL + preL + bL)*(1-g)
      const u16* bpl = cwTL + ((size_t)(i << 10) + d) * 40;
      const u16* bpg = cwTG + ((size_t)(i << 10) + d) * 40;
      const bf16x8 cl0 = *(const bf16x8*)(bpl + quad * 8);
      const bf16x8 cl1 = *(const bf16x8*)(bpl + 32 + quad * 8);
      const bf16x8 cg0 = *(const bf16x8*)(bpg + quad * 8);
      const bf16x8 cg1 = *(const bf16x8*)(bpg + 32 + quad * 8);
      f32x4 aqL[3], aqG[3];
#pragma unroll
      for (int mt2 = 0; mt2 < 3; ++mt2) {
        aqL[mt2] = (f32x4){0.f, 0.f, 0.f, 0.f};
        aqL[mt2] = MFMA_BF16(afA[mt2][0], cl0, aqL[mt2]);
        aqL[mt2] = MFMA_BF16(afA[mt2][1], cl1, aqL[mt2]);
        aqG[mt2] = (f32x4){0.f, 0.f, 0.f, 0.f};
        aqG[mt2] = MFMA_BF16(afA[mt2][0], cg0, aqG[mt2]);
        aqG[mt2] = MFMA_BF16(afA[mt2][1], cg1, aqG[mt2]);
      }
      const float bLv = bL[d], bGv = bG[d];
#pragma unroll
      for (int mt2 = 0; mt2 < 3; ++mt2)
#pragma unroll
        for (int rg = 0; rg < 4; ++rg) {
          const int t = mt2 * 16 + quad * 4 + rg;
          if (t < 40) {
            const size_t ctd = ((size_t)(c * 40 + t) << 10) + d;
            const float aL = aqL[mt2][rg] + bf2f(preL[ctd]) + bLv;
            const float aG = aqG[mt2][rg] + bf2f(preG[ctd]) + bGv;
            const float g = 1.f / (1.f + __expf(-aG));
            const float u = 2.f / (1.f + __expf(-2.f * aL)) - 1.f;  // tanh
            q2o[((size_t)(pair * 40 + t) << 10) + d] =
                f2bf(capf[ctd] * g + u * (1.f - g));
          }
        }
    }
  }
#pragma unroll
  for (int k = 0; k < 12; ++k) {
#pragma unroll
    for (int off = 1; off <= 8; off <<= 1) {
      pn[k] += __shfl_xor(pn[k], off, 64);
      pw[k] += __shfl_xor(pw[k], off, 64);
    }
  }
  __syncthreads();
  if (l15 == 0) {
#pragma unroll
    for (int mt2 = 0; mt2 < 3; ++mt2)
#pragma unroll
      for (int rg = 0; rg < 4; ++rg) {
        const int t = mt2 * 16 + quad * 4 + rg;
        if (t < 40) {
          atomicAdd(&lsCOS[t], pn[mt2 * 4 + rg]);
          atomicAdd(&lsWN[t], pw[mt2 * 4 + rg]);
        }
      }
  }
  __syncthreads();
  if (tid < 40) {
    const float w2 = sqrtf(lsWN[tid]);
    lsRED[tid] = lsCOS[tid] / fmaxf(cnorm[c * 40 + tid] * w2, 1e-8f);
  }
  __syncthreads();
  if (tid == 0) {
    float s = 0.f;
    for (int t = 0; t < 40; ++t) s += lsRED[t];
    s *= (1.f / 40.f);
    if (ITER == 1) sim1[pair] = s;
    else score[i * 32 + c] = s + sim1[pair];
  }
}

// ---------------------------------------------------------------------------
extern "C" void kernel_launch(void* const* d_in, const int* in_sizes, int n_in,
                              void* d_out, int out_size, void* d_ws, size_t ws_size,
                              hipStream_t stream) {
  const float* img = (const float*)d_in[0];   // [32][36][1024] fp32
  const float* cap = (const float*)d_in[1];   // [32][40][1024] fp32
  const float* Wl  = (const float*)d_in[2];   // [2048][1024] fp32
  const float* bl  = (const float*)d_in[3];   // [1024] fp32
  const float* Wg  = (const float*)d_in[4];
  const float* bg  = (const float*)d_in[5];
  float* out = (float*)d_out;                 // [32][32] fp32

  char* ws = (char*)d_ws;                 // total ~120 MB
  float* cnrm = (float*)ws;               ws += 5120;
  float* sim1 = (float*)ws;               ws += 4096;
  u16*   WTl  = (u16*)ws;                 ws += (size_t)1024 * 2048 * 2;   // 4.2 MB
  u16*   WTg  = (u16*)ws;                 ws += (size_t)1024 * 2048 * 2;   // 4.2 MB
  u16*   preL = (u16*)ws;                 ws += (size_t)1280 * 1024 * 2;   // 2.6 MB
  u16*   preG = (u16*)ws;                 ws += (size_t)1280 * 1024 * 2;   // 2.6 MB
  u16*   imgb = (u16*)ws;                 ws += (size_t)1152 * 1024 * 2;   // 2.4 MB
  u16*   capb = (u16*)ws;                 ws += (size_t)1280 * 1024 * 2;   // 2.6 MB
  u16*   ctxT = (u16*)ws;                 ws += (size_t)32 * 1024 * 40 * 2 + 256;
  u16*   cwTL = (u16*)ws;                 ws += (size_t)32 * 1024 * 40 * 2 + 256;
  u16*   cwTG = (u16*)ws;                 ws += (size_t)32 * 1024 * 40 * 2 + 256;
  float* cwL  = (float*)ws;               ws += (size_t)1152 * 1024 * 4;   // 4.7 MB
  float* cwG  = (float*)ws;               ws += (size_t)1152 * 1024 * 4;   // 4.7 MB
  u16*   q2   = (u16*)ws;                 ws += (size_t)40960 * 1024 * 2;  // 83.9 MB

  cvt_k<<<1152, 256, 0, stream>>>(img, imgb);
  cvt_k<<<1280, 256, 0, stream>>>(cap, capb);
  ctxt_k<<<128, 256, 0, stream>>>(img, ctxT);
  transpose_k<<<dim3(64, 32, 2), dim3(32, 8), 0, stream>>>(Wl, Wg, WTl, WTg);
  capnorm_k<<<320, 256, 0, stream>>>(cap, cnrm);
  gemm_w<0><<<80, 256, 0, stream>>>(capb, WTl, WTg, preL, preG);   // cap@W_top
  gemm_w<1><<<72, 256, 0, stream>>>(imgb, WTl, WTg, cwL, cwG);     // img@W_bot
  cwt_k<<<128, 256, 0, stream>>>(cwL, cwTL);
  cwt_k<<<128, 256, 0, stream>>>(cwG, cwTG);
  attn_k<1><<<1024, 256, 0, stream>>>(imgb, capb, q2, ctxT, cwTL, cwTG, preL, preG,
                                      cap, bl, bg, q2, cnrm, sim1, out);
  attn_k<2><<<1024, 256, 0, stream>>>(imgb, capb, q2, ctxT, cwTL, cwTG, preL, preG,
                                      cap, bl, bg, q2, cnrm, sim1, out);
}